// Round 11
// baseline (660.053 us; speedup 1.0000x reference)
//
#include <hip/hip_runtime.h>
#include <hip/hip_bf16.h>

#define D_ 128

typedef __attribute__((ext_vector_type(8))) short s8b;   // 8 bf16
typedef __attribute__((ext_vector_type(4))) float f4;    // MFMA acc

union U4 { uint u[4]; s8b v; uint4 q; };

// async global->LDS, 16B per lane, dest = uniform base + lane*16 (linear)
__device__ __forceinline__ void gl16(const void* g, void* lds) {
    __builtin_amdgcn_global_load_lds(
        (const __attribute__((address_space(1))) void*)g,
        (__attribute__((address_space(3))) void*)lds, 16, 0, 0);
}

// split two fp32 into packed bf16 high (truncate) + low (RNE of residual)
__device__ __forceinline__ void split2(float f0, float f1, uint& hp, uint& lp) {
    uint u0 = __float_as_uint(f0), u1 = __float_as_uint(f1);
    hp = (u0 >> 16) | (u1 & 0xffff0000u);
    float r0 = f0 - __uint_as_float(u0 & 0xffff0000u);
    float r1 = f1 - __uint_as_float(u1 & 0xffff0000u);
    uint v0 = __float_as_uint(r0), v1 = __float_as_uint(r1);
    uint l0 = (v0 + 0x7fffu + ((v0 >> 16) & 1u)) >> 16;
    uint l1 = (v1 + 0x7fffu + ((v1 >> 16) & 1u)) >> 16;
    lp = l0 | (l1 << 16);
}

// ---------------- degree (both relations) ----------------
__global__ void deg2_kernel(const int* __restrict__ dstA, const int* __restrict__ dstB,
                            int* __restrict__ degA, int* __restrict__ degB, int E) {
    int e = blockIdx.x * blockDim.x + threadIdx.x;
    const int* dst = blockIdx.y ? dstB : dstA;
    int* deg = blockIdx.y ? degB : degA;
    if (e < E) atomicAdd(&deg[dst[e]], 1);
}

// ---------------- exclusive scan (3-kernel, both relations) ----------------
__global__ __launch_bounds__(256)
void scan1m(const int* __restrict__ degA, const int* __restrict__ degB,
            int* __restrict__ rpA, int* __restrict__ rpB,
            int* __restrict__ partA, int* __restrict__ partB, int N) {
    const int* deg = blockIdx.y ? degB : degA;
    int* rp = blockIdx.y ? rpB : rpA;
    int* partials = blockIdx.y ? partB : partA;
    int tid = threadIdx.x;
    int i = blockIdx.x * 256 + tid;
    int v = (i < N) ? deg[i] : 0;
    int lane = tid & 63, wid = tid >> 6;
    int x = v;
#pragma unroll
    for (int off = 1; off < 64; off <<= 1) {
        int y = __shfl_up(x, off, 64);
        if (lane >= off) x += y;
    }
    __shared__ int wsum[5];
    if (lane == 63) wsum[wid] = x;
    __syncthreads();
    if (tid == 0) {
        int a = wsum[0], b = wsum[1], c = wsum[2], d = wsum[3];
        wsum[0] = 0; wsum[1] = a; wsum[2] = a + b; wsum[3] = a + b + c;
        wsum[4] = a + b + c + d;
    }
    __syncthreads();
    if (i < N) rp[i] = wsum[wid] + x - v;
    if (tid == 0) partials[blockIdx.x] = wsum[4];
}

__global__ __launch_bounds__(1024)
void scan2m(int* __restrict__ partA, int* __restrict__ partB, int B) {
    int* partials = blockIdx.x ? partB : partA;
    __shared__ int buf[1024];
    int t = threadIdx.x;
    int v = (t < B) ? partials[t] : 0;
    buf[t] = v;
    __syncthreads();
    for (int off = 1; off < 1024; off <<= 1) {
        int add = (t >= off) ? buf[t - off] : 0;
        __syncthreads();
        buf[t] += add;
        __syncthreads();
    }
    if (t < B) partials[t] = buf[t] - v;
}

__global__ __launch_bounds__(256)
void scan3m(int* __restrict__ rpA, int* __restrict__ rpB,
            const int* __restrict__ partA, const int* __restrict__ partB, int N, int E) {
    int* rp = blockIdx.y ? rpB : rpA;
    const int* partials = blockIdx.y ? partB : partA;
    int i = blockIdx.x * 256 + threadIdx.x;
    if (i < N) rp[i] += partials[blockIdx.x];
    if (i == 0) rp[N] = E;
}

// ---------------- CSR fill (both relations) + first-4 pack ----------------
__global__ void fill2_csr(const int* __restrict__ srcA, const int* __restrict__ dstA,
                          const int* __restrict__ rpA, int* __restrict__ curA,
                          int* __restrict__ colA, int* __restrict__ colpA,
                          const int* __restrict__ srcB, const int* __restrict__ dstB,
                          const int* __restrict__ rpB, int* __restrict__ curB,
                          int* __restrict__ colB, int* __restrict__ colpB, int E) {
    int e = blockIdx.x * blockDim.x + threadIdx.x;
    if (e >= E) return;
    const int* src = blockIdx.y ? srcB : srcA;
    const int* dst = blockIdx.y ? dstB : dstA;
    const int* rp  = blockIdx.y ? rpB : rpA;
    int* cursor = blockIdx.y ? curB : curA;
    int* col    = blockIdx.y ? colB : colA;
    int* colp   = blockIdx.y ? colpB : colpA;
    int d = dst[e];
    int s = src[e];
    int idx = atomicAdd(&cursor[d], 1);
    col[rp[d] + idx] = s;
    if (idx < 4) colp[d * 4 + idx] = s;
}

// ---------------- gather-mean: 4 nodes/wave (16 lanes each), first-4 via colp ----------------
// input rows: fp32 [128 f] (INHL=0) or hl [128 bf16h][128 bf16l] (INHL=1). Output: hl.
__device__ __forceinline__ void acc8hl(float* a, uint4 h4, uint4 l4, float wgt) {
    const ushort* hu = (const ushort*)&h4;
    const ushort* lu = (const ushort*)&l4;
#pragma unroll
    for (int j = 0; j < 8; ++j) {
        float v = __uint_as_float((uint)hu[j] << 16) + __uint_as_float((uint)lu[j] << 16);
        a[j] = fmaf(v, wgt, a[j]);
    }
}
__device__ __forceinline__ void acc8f(float* a, float4 u0, float4 u1, float wgt) {
    a[0] = fmaf(u0.x, wgt, a[0]); a[1] = fmaf(u0.y, wgt, a[1]);
    a[2] = fmaf(u0.z, wgt, a[2]); a[3] = fmaf(u0.w, wgt, a[3]);
    a[4] = fmaf(u1.x, wgt, a[4]); a[5] = fmaf(u1.y, wgt, a[5]);
    a[6] = fmaf(u1.z, wgt, a[6]); a[7] = fmaf(u1.w, wgt, a[7]);
}

template<int INHL>
__device__ __forceinline__ void gather_node(const char* x, const int* rp,
        const int* col, const int* colp, ushort* out, int node, int li) {
    int beg = rp[node], end = rp[node + 1];
    int dg = end - beg;
    int4 c4 = *(const int4*)(colp + (size_t)node * 4);
    int s0 = dg > 0 ? c4.x : 0;
    int s1 = dg > 1 ? c4.y : 0;
    int s2 = dg > 2 ? c4.z : 0;
    int s3 = dg > 3 ? c4.w : 0;
    float w0 = dg > 0 ? 1.f : 0.f;
    float w1 = dg > 1 ? 1.f : 0.f;
    float w2 = dg > 2 ? 1.f : 0.f;
    float w3 = dg > 3 ? 1.f : 0.f;
    float a[8];
#pragma unroll
    for (int j = 0; j < 8; ++j) a[j] = 0.f;

    if (INHL) {
        const char* p0 = x + (size_t)s0 * 512 + li * 16;
        const char* p1 = x + (size_t)s1 * 512 + li * 16;
        const char* p2 = x + (size_t)s2 * 512 + li * 16;
        const char* p3 = x + (size_t)s3 * 512 + li * 16;
        uint4 H0 = *(const uint4*)p0, L0 = *(const uint4*)(p0 + 256);
        uint4 H1 = *(const uint4*)p1, L1 = *(const uint4*)(p1 + 256);
        uint4 H2 = *(const uint4*)p2, L2 = *(const uint4*)(p2 + 256);
        uint4 H3 = *(const uint4*)p3, L3 = *(const uint4*)(p3 + 256);
        acc8hl(a, H0, L0, w0); acc8hl(a, H1, L1, w1);
        acc8hl(a, H2, L2, w2); acc8hl(a, H3, L3, w3);
    } else {
        const char* p0 = x + (size_t)s0 * 512 + li * 32;
        const char* p1 = x + (size_t)s1 * 512 + li * 32;
        const char* p2 = x + (size_t)s2 * 512 + li * 32;
        const char* p3 = x + (size_t)s3 * 512 + li * 32;
        float4 A0 = *(const float4*)p0, B0 = *(const float4*)(p0 + 16);
        float4 A1 = *(const float4*)p1, B1 = *(const float4*)(p1 + 16);
        float4 A2 = *(const float4*)p2, B2 = *(const float4*)(p2 + 16);
        float4 A3 = *(const float4*)p3, B3 = *(const float4*)(p3 + 16);
        acc8f(a, A0, B0, w0); acc8f(a, A1, B1, w1);
        acc8f(a, A2, B2, w2); acc8f(a, A3, B3, w3);
    }
    for (int e = beg + 4; e < end; ++e) {       // rare tail (deg>4)
        int s = col[e];
        if (INHL) {
            const char* p = x + (size_t)s * 512 + li * 16;
            acc8hl(a, *(const uint4*)p, *(const uint4*)(p + 256), 1.f);
        } else {
            const char* p = x + (size_t)s * 512 + li * 32;
            acc8f(a, *(const float4*)p, *(const float4*)(p + 16), 1.f);
        }
    }
    float inv = 1.f / (float)(dg > 0 ? dg : 1);
    uint h0, h1, h2, h3, l0, l1, l2, l3;
    split2(a[0] * inv, a[1] * inv, h0, l0);
    split2(a[2] * inv, a[3] * inv, h1, l1);
    split2(a[4] * inv, a[5] * inv, h2, l2);
    split2(a[6] * inv, a[7] * inv, h3, l3);
    char* ob = (char*)out + (size_t)node * 512;
    *(uint4*)(ob + li * 16) = make_uint4(h0, h1, h2, h3);
    *(uint4*)(ob + 256 + li * 16) = make_uint4(l0, l1, l2, l3);
}

template<int INHL>
__global__ __launch_bounds__(256)
void gather2k(const void* xA, const int* rpA, const int* colA, const int* colpA,
              ushort* outA, int NA,
              const void* xB, const int* rpB, const int* colB, const int* colpB,
              ushort* outB, int NB, int blocksA) {
    bool isA = (int)blockIdx.x < blocksA;
    int bid = isA ? blockIdx.x : blockIdx.x - blocksA;
    long long gid = (long long)bid * 256 + threadIdx.x;
    int node = (int)(gid >> 4);
    int li = (int)(gid & 15);
    if (isA) { if (node < NA) gather_node<INHL>((const char*)xA, rpA, colA, colpA, outA, node, li); }
    else     { if (node < NB) gather_node<INHL>((const char*)xB, rpB, colB, colpB, outB, node, li); }
}

// ---------------- weight prep: transpose + bf16 h/l split ----------------
// WT layout per config g: [col 0..127][kv 0..255] (kv<128 self, >=128 neigh)
__global__ __launch_bounds__(256)
void prep_weights(const float* __restrict__ s0, const float* __restrict__ n0,
                  const float* __restrict__ s1, const float* __restrict__ n1,
                  const float* __restrict__ s2, const float* __restrict__ n2,
                  const float* __restrict__ s3, const float* __restrict__ n3,
                  ushort* __restrict__ WTH, ushort* __restrict__ WTL) {
    int g = blockIdx.y;
    int t = blockIdx.x * 256 + threadIdx.x;   // 0..4095
    int c = t & 127;
    int oct = t >> 7;                          // 0..31 (8 kv each)
    const float* self  = g == 0 ? s0 : g == 1 ? s1 : g == 2 ? s2 : s3;
    const float* neigh = g == 0 ? n0 : g == 1 ? n1 : g == 2 ? n2 : n3;
    uint hd[4], ld_[4];
#pragma unroll
    for (int p = 0; p < 4; ++p) {
        uint hpair = 0, lpair = 0;
#pragma unroll
        for (int q = 0; q < 2; ++q) {
            int kv = oct * 8 + p * 2 + q;
            const float* Wsrc = kv < 128 ? self : neigh;
            float f = Wsrc[(size_t)(kv & 127) * 128 + c];
            uint u = __float_as_uint(f);
            uint h = u >> 16;
            float r = f - __uint_as_float(u & 0xffff0000u);
            uint v = __float_as_uint(r);
            uint l = (v + 0x7fffu + ((v >> 16) & 1u)) >> 16;
            hpair |= h << (16 * q);
            lpair |= l << (16 * q);
        }
        hd[p] = hpair; ld_[p] = lpair;
    }
    size_t base = ((size_t)g * 128 + c) * 256 + oct * 8;
    *(uint4*)(WTH + base) = make_uint4(hd[0], hd[1], hd[2], hd[3]);
    *(uint4*)(WTL + base) = make_uint4(ld_[0], ld_[1], ld_[2], ld_[3]);
}

// ---------------- MFMA GEMM: 64x128 block tile, 4 waves of 32x64, occupancy-tuned ----------------
// out[N,128] = A1@W_self + A2@W_neigh + bias, compensated bf16 (Ah@Wh+Al@Wh+Ah@Wl).
// 8 K-steps of 32 (0-3 A1, 4-7 A2), single LDS buffer, sync staging via global_load_lds.
// LDS: Ah[0,4K) Al[4K,8K) (fp32 A1 variant uses [0,8K)); Wh[8K,16K) Wl[16K,24K).
// Swizzle: linear LDS dest, source chunk cs^((row>>1)&3) (2-way = free), reads match.
// Regs: 12 frag s8b (48v) + acc 32a -> ~110 total => 4 waves/SIMD (launch_bounds pinned).
template<int A1FP32, int SPLIT, int LRELU>
__device__ __forceinline__ void gemm_body(const void* A1, const void* A2,
        const ushort* WTh, const ushort* WTl, const float* bias, void* outp,
        int N, int bid, char* smem) {
    const int t = threadIdx.x;
    const int w = t >> 6, lane = t & 63;
    const int fr = lane & 15, hi = lane >> 4;
    const int mrow0 = (w & 1) * 32, ncol0 = (w >> 1) * 64;
    const int row0 = bid * 64;

    f4 acc[2][4];
    {
        float bv[4];
#pragma unroll
        for (int n = 0; n < 4; ++n) bv[n] = bias[ncol0 + n * 16 + fr];
#pragma unroll
        for (int m = 0; m < 2; ++m)
#pragma unroll
            for (int n = 0; n < 4; ++n) acc[m][n] = (f4){bv[n], bv[n], bv[n], bv[n]};
    }

    for (int ks = 0; ks < 8; ++ks) {
        // ---- stage A tile (async, source-swizzled, linear dest)
        if (A1FP32 && ks < 4) {
            const char* src = (const char*)A1;
#pragma unroll
            for (int it = 0; it < 2; ++it) {
                int j = it * 256 + t;            // 0..511 (64 rows x 8 chunks)
                int row = j >> 3, cs = j & 7;
                int gr = row0 + row; gr = gr < N ? gr : N - 1;
                gl16(src + (size_t)gr * 512 + ks * 128 + ((cs ^ (row & 7)) * 16),
                     smem + j * 16);
            }
        } else {
            const char* src = (ks < 4) ? (const char*)A1 : (const char*)A2;
            const int kk = ks & 3;
            {
                int j = t;                        // 0..255 (64 rows x 4 chunks)
                int row = j >> 2, cs = j & 3;
                int gr = row0 + row; gr = gr < N ? gr : N - 1;
                size_t so = (size_t)gr * 512 + kk * 64 + ((cs ^ ((row >> 1) & 3)) * 16);
                gl16(src + so, smem + j * 16);              // Ah
                gl16(src + so + 256, smem + 4096 + j * 16); // Al
            }
        }
        // ---- stage W tile (128 cols x 4 chunks each for Wh, Wl)
        {
#pragma unroll
            for (int it = 0; it < 2; ++it) {
                int j = it * 256 + t;            // 0..511
                int col = j >> 2, cs = j & 3;
                size_t so = (size_t)col * 512 + ks * 64 + ((cs ^ ((col >> 1) & 3)) * 16);
                gl16((const char*)WTh + so, smem + 8192 + j * 16);
                gl16((const char*)WTl + so, smem + 16384 + j * 16);
            }
        }
        __syncthreads();

        // ---- fragments from LDS (swizzled reads), 24 MFMAs/wave
        s8b ah[2], al[2], wh[4], wl[4];
        if (A1FP32 && ks < 4) {
#pragma unroll
            for (int m = 0; m < 2; ++m) {
                int r = mrow0 + m * 16 + fr;
                f4 x0 = *(const f4*)(smem + r * 128 + (((hi * 2) ^ (r & 7)) * 16));
                f4 x1 = *(const f4*)(smem + r * 128 + (((hi * 2 + 1) ^ (r & 7)) * 16));
                U4 H, L;
                split2(x0[0], x0[1], H.u[0], L.u[0]);
                split2(x0[2], x0[3], H.u[1], L.u[1]);
                split2(x1[0], x1[1], H.u[2], L.u[2]);
                split2(x1[2], x1[3], H.u[3], L.u[3]);
                ah[m] = H.v; al[m] = L.v;
            }
        } else {
#pragma unroll
            for (int m = 0; m < 2; ++m) {
                int r = mrow0 + m * 16 + fr;
                int off = r * 64 + ((hi ^ ((r >> 1) & 3)) * 16);
                ah[m] = *(const s8b*)(smem + off);
                al[m] = *(const s8b*)(smem + 4096 + off);
            }
        }
#pragma unroll
        for (int n = 0; n < 4; ++n) {
            int c = ncol0 + n * 16 + fr;
            int off = c * 64 + ((hi ^ ((c >> 1) & 3)) * 16);
            wh[n] = *(const s8b*)(smem + 8192 + off);
            wl[n] = *(const s8b*)(smem + 16384 + off);
        }
#pragma unroll
        for (int n = 0; n < 4; ++n)
#pragma unroll
            for (int m = 0; m < 2; ++m) {
                acc[m][n] = __builtin_amdgcn_mfma_f32_16x16x32_bf16(ah[m], wh[n], acc[m][n], 0, 0, 0);
                acc[m][n] = __builtin_amdgcn_mfma_f32_16x16x32_bf16(al[m], wh[n], acc[m][n], 0, 0, 0);
                acc[m][n] = __builtin_amdgcn_mfma_f32_16x16x32_bf16(ah[m], wl[n], acc[m][n], 0, 0, 0);
            }
        __syncthreads();
    }

    // ---- epilogue: single-pass LDS transpose (64 rows x 132 floats = 33.8KB)
    float* T = (float*)smem;
#pragma unroll
    for (int m = 0; m < 2; ++m)
#pragma unroll
        for (int n = 0; n < 4; ++n)
#pragma unroll
            for (int r = 0; r < 4; ++r)
                T[(mrow0 + m * 16 + hi * 4 + r) * 132 + ncol0 + n * 16 + fr] = acc[m][n][r];
    __syncthreads();
    {
        int gr = row0 + lane;                   // lane -> row, wave -> 32-col chunk
        if (gr < N) {
            const float* p = T + lane * 132 + w * 32;
#pragma unroll
            for (int half = 0; half < 2; ++half) {
                f4 x0 = *(const f4*)(p + half * 16);
                f4 x1 = *(const f4*)(p + half * 16 + 4);
                f4 x2 = *(const f4*)(p + half * 16 + 8);
                f4 x3 = *(const f4*)(p + half * 16 + 12);
                float e[16] = {x0[0], x0[1], x0[2], x0[3], x1[0], x1[1], x1[2], x1[3],
                               x2[0], x2[1], x2[2], x2[3], x3[0], x3[1], x3[2], x3[3]};
                if (LRELU) {
#pragma unroll
                    for (int i = 0; i < 16; ++i) e[i] = e[i] > 0.f ? e[i] : 0.01f * e[i];
                }
                if (SPLIT) {
                    uint h[8], l[8];
#pragma unroll
                    for (int i = 0; i < 8; ++i) split2(e[2 * i], e[2 * i + 1], h[i], l[i]);
                    char* ob = (char*)outp + (size_t)gr * 512 + w * 64 + half * 32;
                    *(uint4*)ob = make_uint4(h[0], h[1], h[2], h[3]);
                    *(uint4*)(ob + 16) = make_uint4(h[4], h[5], h[6], h[7]);
                    *(uint4*)(ob + 256) = make_uint4(l[0], l[1], l[2], l[3]);
                    *(uint4*)(ob + 272) = make_uint4(l[4], l[5], l[6], l[7]);
                } else {
                    float* ob = (float*)outp + (size_t)gr * 128 + w * 32 + half * 16;
#pragma unroll
                    for (int i = 0; i < 4; ++i)
                        *(float4*)(ob + i * 4) = make_float4(e[i * 4], e[i * 4 + 1],
                                                             e[i * 4 + 2], e[i * 4 + 3]);
                }
            }
        }
    }
}

template<int A1FP32, int SPLIT, int LRELU>
__global__ __launch_bounds__(256, 4)
void gemm2k(const void* A1a, const void* A2a, const ushort* WTha, const ushort* WTla,
            const float* ba, void* outa, int Na,
            const void* A1b, const void* A2b, const ushort* WThb, const ushort* WTlb,
            const float* bb, void* outb, int Nb, int blocksA) {
    __shared__ __align__(16) char smem[33792];
    bool isA = (int)blockIdx.x < blocksA;
    int bid = isA ? blockIdx.x : blockIdx.x - blocksA;
    if (isA) gemm_body<A1FP32, SPLIT, LRELU>(A1a, A2a, WTha, WTla, ba, outa, Na, bid, smem);
    else     gemm_body<A1FP32, SPLIT, LRELU>(A1b, A2b, WThb, WTlb, bb, outb, Nb, bid, smem);
}

extern "C" void kernel_launch(void* const* d_in, const int* in_sizes, int n_in,
                              void* d_out, int out_size, void* d_ws, size_t ws_size,
                              hipStream_t stream) {
    const float* x_user     = (const float*)d_in[0];
    const float* x_item     = (const float*)d_in[1];
    const float* w1_self_uc = (const float*)d_in[2];
    const float* w1_neigh_uc= (const float*)d_in[3];
    const float* b1_uc      = (const float*)d_in[4];
    const float* w1_self_iu = (const float*)d_in[5];
    const float* w1_neigh_iu= (const float*)d_in[6];
    const float* b1_iu      = (const float*)d_in[7];
    const float* w2_self_uc = (const float*)d_in[8];
    const float* w2_neigh_uc= (const float*)d_in[9];
    const float* b2_uc      = (const float*)d_in[10];
    const float* w2_self_iu = (const float*)d_in[11];
    const float* w2_neigh_iu= (const float*)d_in[12];
    const float* b2_iu      = (const float*)d_in[13];
    const int* src_uc = (const int*)d_in[14];
    const int* dst_uc = (const int*)d_in[15];
    const int* src_iu = (const int*)d_in[16];
    const int* dst_iu = (const int*)d_in[17];

    const int NU = in_sizes[0] / D_;
    const int NI = in_sizes[1] / D_;
    const int E  = in_sizes[14];

    // d_out halves: [h2_user; h2_item]. During layers they hold h1 in hl form.
    char* hl_user = (char*)d_out;                        // NU rows x 512B
    char* hl_item = (char*)d_out + (size_t)NU * 512;     // NI rows x 512B
    float* f_user = (float*)d_out;
    float* f_item = (float*)d_out + (size_t)NU * 128;

    // workspace layout
    char* ws = (char*)d_ws;
    const size_t FEAT_BYTES = (size_t)200000 * 512;      // 102.4 MB (hl rows)
    ushort* agg_i  = (ushort*)ws; ws += FEAT_BYTES;
    ushort* agg_u  = (ushort*)ws; ws += FEAT_BYTES;
    ushort* WTH    = (ushort*)ws; ws += (size_t)4 * 128 * 256 * sizeof(ushort);
    ushort* WTL    = (ushort*)ws; ws += (size_t)4 * 128 * 256 * sizeof(ushort);
    int* colp_uc   = (int*)ws;    ws += (size_t)200000 * 4 * sizeof(int);
    int* colp_iu   = (int*)ws;    ws += (size_t)200000 * 4 * sizeof(int);
    int* rp_uc     = (int*)ws;    ws += (size_t)(NI + 1) * sizeof(int);
    int* rp_iu     = (int*)ws;    ws += (size_t)(NU + 1) * sizeof(int);
    int* col_uc    = (int*)ws;    ws += (size_t)E * sizeof(int);
    int* col_iu    = (int*)ws;    ws += (size_t)E * sizeof(int);
    int* deg_uc    = (int*)ws;    ws += (size_t)200000 * sizeof(int);
    int* deg_iu    = (int*)ws;    ws += (size_t)200000 * sizeof(int);
    int* cur_uc    = (int*)ws;    ws += (size_t)200000 * sizeof(int);
    int* cur_iu    = (int*)ws;    ws += (size_t)200000 * sizeof(int);
    int* partA     = (int*)ws;    ws += (size_t)1024 * sizeof(int);
    int* partB     = (int*)ws;    ws += (size_t)1024 * sizeof(int);

    const int TPB = 256;
    const int eBlocks  = (E + TPB - 1) / TPB;
    const int sBlocks  = (200000 + 255) / 256;
    const int gBlocksI = (int)(((long long)NI * 16 + TPB - 1) / TPB);
    const int gBlocksU = (int)(((long long)NU * 16 + TPB - 1) / TPB);
    const int mBlocksI = (NI + 63) / 64;
    const int mBlocksU = (NU + 63) / 64;
    const size_t WSTRIDE = (size_t)128 * 256;  // g0=l1_uc g1=l1_iu g2=l2_uc g3=l2_iu

    hipMemsetAsync(deg_uc, 0, (size_t)4 * 200000 * sizeof(int), stream); // deg+cursor both rel

    prep_weights<<<dim3(16, 4), 256, 0, stream>>>(
        w1_self_uc, w1_neigh_uc, w1_self_iu, w1_neigh_iu,
        w2_self_uc, w2_neigh_uc, w2_self_iu, w2_neigh_iu, WTH, WTL);

    deg2_kernel<<<dim3(eBlocks, 2), TPB, 0, stream>>>(dst_uc, dst_iu, deg_uc, deg_iu, E);
    scan1m<<<dim3(sBlocks, 2), 256, 0, stream>>>(deg_uc, deg_iu, rp_uc, rp_iu, partA, partB, 200000);
    scan2m<<<2, 1024, 0, stream>>>(partA, partB, sBlocks);
    scan3m<<<dim3(sBlocks, 2), 256, 0, stream>>>(rp_uc, rp_iu, partA, partB, 200000, E);
    fill2_csr<<<dim3(eBlocks, 2), TPB, 0, stream>>>(src_uc, dst_uc, rp_uc, cur_uc, col_uc, colp_uc,
                                                    src_iu, dst_iu, rp_iu, cur_iu, col_iu, colp_iu, E);

    // ---- layer 1: gather fp32 x -> hl agg; GEMM (A1 fp32) -> h1 hl into d_out
    gather2k<0><<<gBlocksI + gBlocksU, TPB, 0, stream>>>(
        x_user, rp_uc, col_uc, colp_uc, agg_i, NI,
        x_item, rp_iu, col_iu, colp_iu, agg_u, NU, gBlocksI);
    gemm2k<1, 1, 1><<<mBlocksI + mBlocksU, TPB, 0, stream>>>(
        x_item, agg_i, WTH + 0 * WSTRIDE, WTL + 0 * WSTRIDE, b1_uc, hl_item, NI,
        x_user, agg_u, WTH + 1 * WSTRIDE, WTL + 1 * WSTRIDE, b1_iu, hl_user, NU,
        mBlocksI);

    // ---- layer 2: gather hl h1 -> hl agg; GEMM (A1 hl, in-place) -> fp32 d_out
    gather2k<1><<<gBlocksI + gBlocksU, TPB, 0, stream>>>(
        hl_user, rp_uc, col_uc, colp_uc, agg_i, NI,
        hl_item, rp_iu, col_iu, colp_iu, agg_u, NU, gBlocksI);
    gemm2k<0, 0, 0><<<mBlocksI + mBlocksU, TPB, 0, stream>>>(
        hl_item, agg_i, WTH + 2 * WSTRIDE, WTL + 2 * WSTRIDE, b2_uc, f_item, NI,
        hl_user, agg_u, WTH + 3 * WSTRIDE, WTL + 3 * WSTRIDE, b2_iu, f_user, NU,
        mBlocksI);
}

// Round 12
// 617.531 us; speedup vs baseline: 1.0689x; 1.0689x over previous
//
#include <hip/hip_runtime.h>
#include <hip/hip_bf16.h>

#define D_ 128

typedef __attribute__((ext_vector_type(8))) short s8b;   // 8 bf16
typedef __attribute__((ext_vector_type(4))) float f4;    // MFMA acc

union U4 { uint u[4]; s8b v; uint4 q; };

// async global->LDS, 16B per lane, dest = uniform base + lane*16 (linear)
__device__ __forceinline__ void gl16(const void* g, void* lds) {
    __builtin_amdgcn_global_load_lds(
        (const __attribute__((address_space(1))) void*)g,
        (__attribute__((address_space(3))) void*)lds, 16, 0, 0);
}

// split two fp32 into packed bf16 high (truncate) + low (RNE of residual)
__device__ __forceinline__ void split2(float f0, float f1, uint& hp, uint& lp) {
    uint u0 = __float_as_uint(f0), u1 = __float_as_uint(f1);
    hp = (u0 >> 16) | (u1 & 0xffff0000u);
    float r0 = f0 - __uint_as_float(u0 & 0xffff0000u);
    float r1 = f1 - __uint_as_float(u1 & 0xffff0000u);
    uint v0 = __float_as_uint(r0), v1 = __float_as_uint(r1);
    uint l0 = (v0 + 0x7fffu + ((v0 >> 16) & 1u)) >> 16;
    uint l1 = (v1 + 0x7fffu + ((v1 >> 16) & 1u)) >> 16;
    lp = l0 | (l1 << 16);
}

// ---------------- degree (both relations) ----------------
__global__ void deg2_kernel(const int* __restrict__ dstA, const int* __restrict__ dstB,
                            int* __restrict__ degA, int* __restrict__ degB, int E) {
    int e = blockIdx.x * blockDim.x + threadIdx.x;
    const int* dst = blockIdx.y ? dstB : dstA;
    int* deg = blockIdx.y ? degB : degA;
    if (e < E) atomicAdd(&deg[dst[e]], 1);
}

// ---------------- exclusive scan (3-kernel, both relations) ----------------
__global__ __launch_bounds__(256)
void scan1m(const int* __restrict__ degA, const int* __restrict__ degB,
            int* __restrict__ rpA, int* __restrict__ rpB,
            int* __restrict__ partA, int* __restrict__ partB, int N) {
    const int* deg = blockIdx.y ? degB : degA;
    int* rp = blockIdx.y ? rpB : rpA;
    int* partials = blockIdx.y ? partB : partA;
    int tid = threadIdx.x;
    int i = blockIdx.x * 256 + tid;
    int v = (i < N) ? deg[i] : 0;
    int lane = tid & 63, wid = tid >> 6;
    int x = v;
#pragma unroll
    for (int off = 1; off < 64; off <<= 1) {
        int y = __shfl_up(x, off, 64);
        if (lane >= off) x += y;
    }
    __shared__ int wsum[5];
    if (lane == 63) wsum[wid] = x;
    __syncthreads();
    if (tid == 0) {
        int a = wsum[0], b = wsum[1], c = wsum[2], d = wsum[3];
        wsum[0] = 0; wsum[1] = a; wsum[2] = a + b; wsum[3] = a + b + c;
        wsum[4] = a + b + c + d;
    }
    __syncthreads();
    if (i < N) rp[i] = wsum[wid] + x - v;
    if (tid == 0) partials[blockIdx.x] = wsum[4];
}

__global__ __launch_bounds__(1024)
void scan2m(int* __restrict__ partA, int* __restrict__ partB, int B) {
    int* partials = blockIdx.x ? partB : partA;
    __shared__ int buf[1024];
    int t = threadIdx.x;
    int v = (t < B) ? partials[t] : 0;
    buf[t] = v;
    __syncthreads();
    for (int off = 1; off < 1024; off <<= 1) {
        int add = (t >= off) ? buf[t - off] : 0;
        __syncthreads();
        buf[t] += add;
        __syncthreads();
    }
    if (t < B) partials[t] = buf[t] - v;
}

__global__ __launch_bounds__(256)
void scan3m(int* __restrict__ rpA, int* __restrict__ rpB,
            const int* __restrict__ partA, const int* __restrict__ partB, int N, int E) {
    int* rp = blockIdx.y ? rpB : rpA;
    const int* partials = blockIdx.y ? partB : partA;
    int i = blockIdx.x * 256 + threadIdx.x;
    if (i < N) rp[i] += partials[blockIdx.x];
    if (i == 0) rp[N] = E;
}

// ---------------- CSR fill (both relations) + first-4 pack ----------------
__global__ void fill2_csr(const int* __restrict__ srcA, const int* __restrict__ dstA,
                          const int* __restrict__ rpA, int* __restrict__ curA,
                          int* __restrict__ colA, int* __restrict__ colpA,
                          const int* __restrict__ srcB, const int* __restrict__ dstB,
                          const int* __restrict__ rpB, int* __restrict__ curB,
                          int* __restrict__ colB, int* __restrict__ colpB, int E) {
    int e = blockIdx.x * blockDim.x + threadIdx.x;
    if (e >= E) return;
    const int* src = blockIdx.y ? srcB : srcA;
    const int* dst = blockIdx.y ? dstB : dstA;
    const int* rp  = blockIdx.y ? rpB : rpA;
    int* cursor = blockIdx.y ? curB : curA;
    int* col    = blockIdx.y ? colB : colA;
    int* colp   = blockIdx.y ? colpB : colpA;
    int d = dst[e];
    int s = src[e];
    int idx = atomicAdd(&cursor[d], 1);
    col[rp[d] + idx] = s;
    if (idx < 4) colp[d * 4 + idx] = s;
}

// ---------------- gather-mean: 4 nodes/wave (16 lanes each), first-4 via colp ----------------
// input rows: fp32 [128 f] (INHL=0) or hl [128 bf16h][128 bf16l] (INHL=1). Output: hl.
__device__ __forceinline__ void acc8hl(float* a, uint4 h4, uint4 l4, float wgt) {
    const ushort* hu = (const ushort*)&h4;
    const ushort* lu = (const ushort*)&l4;
#pragma unroll
    for (int j = 0; j < 8; ++j) {
        float v = __uint_as_float((uint)hu[j] << 16) + __uint_as_float((uint)lu[j] << 16);
        a[j] = fmaf(v, wgt, a[j]);
    }
}
__device__ __forceinline__ void acc8f(float* a, float4 u0, float4 u1, float wgt) {
    a[0] = fmaf(u0.x, wgt, a[0]); a[1] = fmaf(u0.y, wgt, a[1]);
    a[2] = fmaf(u0.z, wgt, a[2]); a[3] = fmaf(u0.w, wgt, a[3]);
    a[4] = fmaf(u1.x, wgt, a[4]); a[5] = fmaf(u1.y, wgt, a[5]);
    a[6] = fmaf(u1.z, wgt, a[6]); a[7] = fmaf(u1.w, wgt, a[7]);
}

template<int INHL>
__device__ __forceinline__ void gather_node(const char* x, const int* rp,
        const int* col, const int* colp, ushort* out, int node, int li) {
    int beg = rp[node], end = rp[node + 1];
    int dg = end - beg;
    int4 c4 = *(const int4*)(colp + (size_t)node * 4);
    int s0 = dg > 0 ? c4.x : 0;
    int s1 = dg > 1 ? c4.y : 0;
    int s2 = dg > 2 ? c4.z : 0;
    int s3 = dg > 3 ? c4.w : 0;
    float w0 = dg > 0 ? 1.f : 0.f;
    float w1 = dg > 1 ? 1.f : 0.f;
    float w2 = dg > 2 ? 1.f : 0.f;
    float w3 = dg > 3 ? 1.f : 0.f;
    float a[8];
#pragma unroll
    for (int j = 0; j < 8; ++j) a[j] = 0.f;

    if (INHL) {
        const char* p0 = x + (size_t)s0 * 512 + li * 16;
        const char* p1 = x + (size_t)s1 * 512 + li * 16;
        const char* p2 = x + (size_t)s2 * 512 + li * 16;
        const char* p3 = x + (size_t)s3 * 512 + li * 16;
        uint4 H0 = *(const uint4*)p0, L0 = *(const uint4*)(p0 + 256);
        uint4 H1 = *(const uint4*)p1, L1 = *(const uint4*)(p1 + 256);
        uint4 H2 = *(const uint4*)p2, L2 = *(const uint4*)(p2 + 256);
        uint4 H3 = *(const uint4*)p3, L3 = *(const uint4*)(p3 + 256);
        acc8hl(a, H0, L0, w0); acc8hl(a, H1, L1, w1);
        acc8hl(a, H2, L2, w2); acc8hl(a, H3, L3, w3);
    } else {
        const char* p0 = x + (size_t)s0 * 512 + li * 32;
        const char* p1 = x + (size_t)s1 * 512 + li * 32;
        const char* p2 = x + (size_t)s2 * 512 + li * 32;
        const char* p3 = x + (size_t)s3 * 512 + li * 32;
        float4 A0 = *(const float4*)p0, B0 = *(const float4*)(p0 + 16);
        float4 A1 = *(const float4*)p1, B1 = *(const float4*)(p1 + 16);
        float4 A2 = *(const float4*)p2, B2 = *(const float4*)(p2 + 16);
        float4 A3 = *(const float4*)p3, B3 = *(const float4*)(p3 + 16);
        acc8f(a, A0, B0, w0); acc8f(a, A1, B1, w1);
        acc8f(a, A2, B2, w2); acc8f(a, A3, B3, w3);
    }
    for (int e = beg + 4; e < end; ++e) {       // rare tail (deg>4)
        int s = col[e];
        if (INHL) {
            const char* p = x + (size_t)s * 512 + li * 16;
            acc8hl(a, *(const uint4*)p, *(const uint4*)(p + 256), 1.f);
        } else {
            const char* p = x + (size_t)s * 512 + li * 32;
            acc8f(a, *(const float4*)p, *(const float4*)(p + 16), 1.f);
        }
    }
    float inv = 1.f / (float)(dg > 0 ? dg : 1);
    uint h0, h1, h2, h3, l0, l1, l2, l3;
    split2(a[0] * inv, a[1] * inv, h0, l0);
    split2(a[2] * inv, a[3] * inv, h1, l1);
    split2(a[4] * inv, a[5] * inv, h2, l2);
    split2(a[6] * inv, a[7] * inv, h3, l3);
    char* ob = (char*)out + (size_t)node * 512;
    *(uint4*)(ob + li * 16) = make_uint4(h0, h1, h2, h3);
    *(uint4*)(ob + 256 + li * 16) = make_uint4(l0, l1, l2, l3);
}

template<int INHL>
__global__ __launch_bounds__(256)
void gather2k(const void* xA, const int* rpA, const int* colA, const int* colpA,
              ushort* outA, int NA,
              const void* xB, const int* rpB, const int* colB, const int* colpB,
              ushort* outB, int NB, int blocksA) {
    bool isA = (int)blockIdx.x < blocksA;
    int bid = isA ? blockIdx.x : blockIdx.x - blocksA;
    long long gid = (long long)bid * 256 + threadIdx.x;
    int node = (int)(gid >> 4);
    int li = (int)(gid & 15);
    if (isA) { if (node < NA) gather_node<INHL>((const char*)xA, rpA, colA, colpA, outA, node, li); }
    else     { if (node < NB) gather_node<INHL>((const char*)xB, rpB, colB, colpB, outB, node, li); }
}

// ---------------- weight prep: transpose + bf16 h/l split ----------------
// WT layout per config g: [col 0..127][kv 0..255] (kv<128 self, >=128 neigh)
__global__ __launch_bounds__(256)
void prep_weights(const float* __restrict__ s0, const float* __restrict__ n0,
                  const float* __restrict__ s1, const float* __restrict__ n1,
                  const float* __restrict__ s2, const float* __restrict__ n2,
                  const float* __restrict__ s3, const float* __restrict__ n3,
                  ushort* __restrict__ WTH, ushort* __restrict__ WTL) {
    int g = blockIdx.y;
    int t = blockIdx.x * 256 + threadIdx.x;   // 0..4095
    int c = t & 127;
    int oct = t >> 7;                          // 0..31 (8 kv each)
    const float* self  = g == 0 ? s0 : g == 1 ? s1 : g == 2 ? s2 : s3;
    const float* neigh = g == 0 ? n0 : g == 1 ? n1 : g == 2 ? n2 : n3;
    uint hd[4], ld_[4];
#pragma unroll
    for (int p = 0; p < 4; ++p) {
        uint hpair = 0, lpair = 0;
#pragma unroll
        for (int q = 0; q < 2; ++q) {
            int kv = oct * 8 + p * 2 + q;
            const float* Wsrc = kv < 128 ? self : neigh;
            float f = Wsrc[(size_t)(kv & 127) * 128 + c];
            uint u = __float_as_uint(f);
            uint h = u >> 16;
            float r = f - __uint_as_float(u & 0xffff0000u);
            uint v = __float_as_uint(r);
            uint l = (v + 0x7fffu + ((v >> 16) & 1u)) >> 16;
            hpair |= h << (16 * q);
            lpair |= l << (16 * q);
        }
        hd[p] = hpair; ld_[p] = lpair;
    }
    size_t base = ((size_t)g * 128 + c) * 256 + oct * 8;
    *(uint4*)(WTH + base) = make_uint4(hd[0], hd[1], hd[2], hd[3]);
    *(uint4*)(WTL + base) = make_uint4(ld_[0], ld_[1], ld_[2], ld_[3]);
}

// ---------------- MFMA GEMM: 64x128 block tile, 4 waves of 32x64 ----------------
// out[N,128] = A1@W_self + A2@W_neigh + bias, compensated bf16 (Ah@Wh+Al@Wh+Ah@Wl).
// 8 K-steps of 32 (0-3 A1, 4-7 A2), single LDS buffer, sync staging via global_load_lds.
// Epilogue: 4 lanes per row cover full 64B sectors per store instruction (no partial-line RMW).
template<int A1FP32, int SPLIT, int LRELU>
__device__ __forceinline__ void gemm_body(const void* A1, const void* A2,
        const ushort* WTh, const ushort* WTl, const float* bias, void* outp,
        int N, int bid, char* smem) {
    const int t = threadIdx.x;
    const int w = t >> 6, lane = t & 63;
    const int fr = lane & 15, hi = lane >> 4;
    const int mrow0 = (w & 1) * 32, ncol0 = (w >> 1) * 64;
    const int row0 = bid * 64;

    f4 acc[2][4];
    {
        float bv[4];
#pragma unroll
        for (int n = 0; n < 4; ++n) bv[n] = bias[ncol0 + n * 16 + fr];
#pragma unroll
        for (int m = 0; m < 2; ++m)
#pragma unroll
            for (int n = 0; n < 4; ++n) acc[m][n] = (f4){bv[n], bv[n], bv[n], bv[n]};
    }

    for (int ks = 0; ks < 8; ++ks) {
        // ---- stage A tile (async, source-swizzled, linear dest)
        if (A1FP32 && ks < 4) {
            const char* src = (const char*)A1;
#pragma unroll
            for (int it = 0; it < 2; ++it) {
                int j = it * 256 + t;            // 0..511 (64 rows x 8 chunks)
                int row = j >> 3, cs = j & 7;
                int gr = row0 + row; gr = gr < N ? gr : N - 1;
                gl16(src + (size_t)gr * 512 + ks * 128 + ((cs ^ (row & 7)) * 16),
                     smem + j * 16);
            }
        } else {
            const char* src = (ks < 4) ? (const char*)A1 : (const char*)A2;
            const int kk = ks & 3;
            {
                int j = t;                        // 0..255 (64 rows x 4 chunks)
                int row = j >> 2, cs = j & 3;
                int gr = row0 + row; gr = gr < N ? gr : N - 1;
                size_t so = (size_t)gr * 512 + kk * 64 + ((cs ^ ((row >> 1) & 3)) * 16);
                gl16(src + so, smem + j * 16);              // Ah
                gl16(src + so + 256, smem + 4096 + j * 16); // Al
            }
        }
        // ---- stage W tile (128 cols x 4 chunks each for Wh, Wl)
        {
#pragma unroll
            for (int it = 0; it < 2; ++it) {
                int j = it * 256 + t;            // 0..511
                int col = j >> 2, cs = j & 3;
                size_t so = (size_t)col * 512 + ks * 64 + ((cs ^ ((col >> 1) & 3)) * 16);
                gl16((const char*)WTh + so, smem + 8192 + j * 16);
                gl16((const char*)WTl + so, smem + 16384 + j * 16);
            }
        }
        __syncthreads();

        // ---- fragments from LDS (swizzled reads), 24 MFMAs/wave
        s8b ah[2], al[2], wh[4], wl[4];
        if (A1FP32 && ks < 4) {
#pragma unroll
            for (int m = 0; m < 2; ++m) {
                int r = mrow0 + m * 16 + fr;
                f4 x0 = *(const f4*)(smem + r * 128 + (((hi * 2) ^ (r & 7)) * 16));
                f4 x1 = *(const f4*)(smem + r * 128 + (((hi * 2 + 1) ^ (r & 7)) * 16));
                U4 H, L;
                split2(x0[0], x0[1], H.u[0], L.u[0]);
                split2(x0[2], x0[3], H.u[1], L.u[1]);
                split2(x1[0], x1[1], H.u[2], L.u[2]);
                split2(x1[2], x1[3], H.u[3], L.u[3]);
                ah[m] = H.v; al[m] = L.v;
            }
        } else {
#pragma unroll
            for (int m = 0; m < 2; ++m) {
                int r = mrow0 + m * 16 + fr;
                int off = r * 64 + ((hi ^ ((r >> 1) & 3)) * 16);
                ah[m] = *(const s8b*)(smem + off);
                al[m] = *(const s8b*)(smem + 4096 + off);
            }
        }
#pragma unroll
        for (int n = 0; n < 4; ++n) {
            int c = ncol0 + n * 16 + fr;
            int off = c * 64 + ((hi ^ ((c >> 1) & 3)) * 16);
            wh[n] = *(const s8b*)(smem + 8192 + off);
            wl[n] = *(const s8b*)(smem + 16384 + off);
        }
#pragma unroll
        for (int n = 0; n < 4; ++n)
#pragma unroll
            for (int m = 0; m < 2; ++m) {
                acc[m][n] = __builtin_amdgcn_mfma_f32_16x16x32_bf16(ah[m], wh[n], acc[m][n], 0, 0, 0);
                acc[m][n] = __builtin_amdgcn_mfma_f32_16x16x32_bf16(al[m], wh[n], acc[m][n], 0, 0, 0);
                acc[m][n] = __builtin_amdgcn_mfma_f32_16x16x32_bf16(ah[m], wl[n], acc[m][n], 0, 0, 0);
            }
        __syncthreads();
    }

    // ---- epilogue: LDS transpose (64 rows x 132 floats = 33.8KB), sector-aligned stores
    float* T = (float*)smem;
#pragma unroll
    for (int m = 0; m < 2; ++m)
#pragma unroll
        for (int n = 0; n < 4; ++n)
#pragma unroll
            for (int r = 0; r < 4; ++r)
                T[(mrow0 + m * 16 + hi * 4 + r) * 132 + ncol0 + n * 16 + fr] = acc[m][n][r];
    __syncthreads();
    {
        int row = t >> 2, q = t & 3;            // 4 lanes per row -> full 64B sectors
        int gr = row0 + row;
        if (gr < N) {
            if (SPLIT) {
                char* ob = (char*)outp + (size_t)gr * 512;
#pragma unroll
                for (int i = 0; i < 4; ++i) {
                    const float* p = T + row * 132 + i * 32 + q * 8;
                    f4 x0 = *(const f4*)p;
                    f4 x1 = *(const f4*)(p + 4);
                    float e[8] = {x0[0], x0[1], x0[2], x0[3], x1[0], x1[1], x1[2], x1[3]};
                    if (LRELU) {
#pragma unroll
                        for (int j = 0; j < 8; ++j) e[j] = e[j] > 0.f ? e[j] : 0.01f * e[j];
                    }
                    uint h[4], l[4];
#pragma unroll
                    for (int j = 0; j < 4; ++j) split2(e[2 * j], e[2 * j + 1], h[j], l[j]);
                    *(uint4*)(ob + i * 64 + q * 16) = make_uint4(h[0], h[1], h[2], h[3]);
                    *(uint4*)(ob + 256 + i * 64 + q * 16) = make_uint4(l[0], l[1], l[2], l[3]);
                }
            } else {
                float* ob = (float*)outp + (size_t)gr * 128;
#pragma unroll
                for (int i = 0; i < 8; ++i) {
                    f4 x = *(const f4*)(T + row * 132 + i * 16 + q * 4);
                    float e0 = x[0], e1 = x[1], e2 = x[2], e3 = x[3];
                    if (LRELU) {
                        e0 = e0 > 0.f ? e0 : 0.01f * e0;
                        e1 = e1 > 0.f ? e1 : 0.01f * e1;
                        e2 = e2 > 0.f ? e2 : 0.01f * e2;
                        e3 = e3 > 0.f ? e3 : 0.01f * e3;
                    }
                    *(float4*)(ob + i * 16 + q * 4) = make_float4(e0, e1, e2, e3);
                }
            }
        }
    }
}

template<int A1FP32, int SPLIT, int LRELU>
__global__ __launch_bounds__(256, 4)
void gemm2k(const void* A1a, const void* A2a, const ushort* WTha, const ushort* WTla,
            const float* ba, void* outa, int Na,
            const void* A1b, const void* A2b, const ushort* WThb, const ushort* WTlb,
            const float* bb, void* outb, int Nb, int blocksA) {
    __shared__ __align__(16) char smem[33792];
    bool isA = (int)blockIdx.x < blocksA;
    int bid = isA ? blockIdx.x : blockIdx.x - blocksA;
    if (isA) gemm_body<A1FP32, SPLIT, LRELU>(A1a, A2a, WTha, WTla, ba, outa, Na, bid, smem);
    else     gemm_body<A1FP32, SPLIT, LRELU>(A1b, A2b, WThb, WTlb, bb, outb, Nb, bid, smem);
}

extern "C" void kernel_launch(void* const* d_in, const int* in_sizes, int n_in,
                              void* d_out, int out_size, void* d_ws, size_t ws_size,
                              hipStream_t stream) {
    const float* x_user     = (const float*)d_in[0];
    const float* x_item     = (const float*)d_in[1];
    const float* w1_self_uc = (const float*)d_in[2];
    const float* w1_neigh_uc= (const float*)d_in[3];
    const float* b1_uc      = (const float*)d_in[4];
    const float* w1_self_iu = (const float*)d_in[5];
    const float* w1_neigh_iu= (const float*)d_in[6];
    const float* b1_iu      = (const float*)d_in[7];
    const float* w2_self_uc = (const float*)d_in[8];
    const float* w2_neigh_uc= (const float*)d_in[9];
    const float* b2_uc      = (const float*)d_in[10];
    const float* w2_self_iu = (const float*)d_in[11];
    const float* w2_neigh_iu= (const float*)d_in[12];
    const float* b2_iu      = (const float*)d_in[13];
    const int* src_uc = (const int*)d_in[14];
    const int* dst_uc = (const int*)d_in[15];
    const int* src_iu = (const int*)d_in[16];
    const int* dst_iu = (const int*)d_in[17];

    const int NU = in_sizes[0] / D_;
    const int NI = in_sizes[1] / D_;
    const int E  = in_sizes[14];

    // d_out halves: [h2_user; h2_item]. During layers they hold h1 in hl form.
    char* hl_user = (char*)d_out;                        // NU rows x 512B
    char* hl_item = (char*)d_out + (size_t)NU * 512;     // NI rows x 512B
    float* f_user = (float*)d_out;
    float* f_item = (float*)d_out + (size_t)NU * 128;

    // workspace layout
    char* ws = (char*)d_ws;
    const size_t FEAT_BYTES = (size_t)200000 * 512;      // 102.4 MB (hl rows)
    ushort* agg_i  = (ushort*)ws; ws += FEAT_BYTES;
    ushort* agg_u  = (ushort*)ws; ws += FEAT_BYTES;
    ushort* WTH    = (ushort*)ws; ws += (size_t)4 * 128 * 256 * sizeof(ushort);
    ushort* WTL    = (ushort*)ws; ws += (size_t)4 * 128 * 256 * sizeof(ushort);
    int* colp_uc   = (int*)ws;    ws += (size_t)200000 * 4 * sizeof(int);
    int* colp_iu   = (int*)ws;    ws += (size_t)200000 * 4 * sizeof(int);
    int* rp_uc     = (int*)ws;    ws += (size_t)(NI + 1) * sizeof(int);
    int* rp_iu     = (int*)ws;    ws += (size_t)(NU + 1) * sizeof(int);
    int* col_uc    = (int*)ws;    ws += (size_t)E * sizeof(int);
    int* col_iu    = (int*)ws;    ws += (size_t)E * sizeof(int);
    int* deg_uc    = (int*)ws;    ws += (size_t)200000 * sizeof(int);
    int* deg_iu    = (int*)ws;    ws += (size_t)200000 * sizeof(int);
    int* cur_uc    = (int*)ws;    ws += (size_t)200000 * sizeof(int);
    int* cur_iu    = (int*)ws;    ws += (size_t)200000 * sizeof(int);
    int* partA     = (int*)ws;    ws += (size_t)1024 * sizeof(int);
    int* partB     = (int*)ws;    ws += (size_t)1024 * sizeof(int);

    const int TPB = 256;
    const int eBlocks  = (E + TPB - 1) / TPB;
    const int sBlocks  = (200000 + 255) / 256;
    const int gBlocksI = (int)(((long long)NI * 16 + TPB - 1) / TPB);
    const int gBlocksU = (int)(((long long)NU * 16 + TPB - 1) / TPB);
    const int mBlocksI = (NI + 63) / 64;
    const int mBlocksU = (NU + 63) / 64;
    const size_t WSTRIDE = (size_t)128 * 256;  // g0=l1_uc g1=l1_iu g2=l2_uc g3=l2_iu

    hipMemsetAsync(deg_uc, 0, (size_t)4 * 200000 * sizeof(int), stream); // deg+cursor both rel

    prep_weights<<<dim3(16, 4), 256, 0, stream>>>(
        w1_self_uc, w1_neigh_uc, w1_self_iu, w1_neigh_iu,
        w2_self_uc, w2_neigh_uc, w2_self_iu, w2_neigh_iu, WTH, WTL);

    deg2_kernel<<<dim3(eBlocks, 2), TPB, 0, stream>>>(dst_uc, dst_iu, deg_uc, deg_iu, E);
    scan1m<<<dim3(sBlocks, 2), 256, 0, stream>>>(deg_uc, deg_iu, rp_uc, rp_iu, partA, partB, 200000);
    scan2m<<<2, 1024, 0, stream>>>(partA, partB, sBlocks);
    scan3m<<<dim3(sBlocks, 2), 256, 0, stream>>>(rp_uc, rp_iu, partA, partB, 200000, E);
    fill2_csr<<<dim3(eBlocks, 2), TPB, 0, stream>>>(src_uc, dst_uc, rp_uc, cur_uc, col_uc, colp_uc,
                                                    src_iu, dst_iu, rp_iu, cur_iu, col_iu, colp_iu, E);

    // ---- layer 1: gather fp32 x -> hl agg; GEMM (A1 fp32) -> h1 hl into d_out
    gather2k<0><<<gBlocksI + gBlocksU, TPB, 0, stream>>>(
        x_user, rp_uc, col_uc, colp_uc, agg_i, NI,
        x_item, rp_iu, col_iu, colp_iu, agg_u, NU, gBlocksI);
    gemm2k<1, 1, 1><<<mBlocksI + mBlocksU, TPB, 0, stream>>>(
        x_item, agg_i, WTH + 0 * WSTRIDE, WTL + 0 * WSTRIDE, b1_uc, hl_item, NI,
        x_user, agg_u, WTH + 1 * WSTRIDE, WTL + 1 * WSTRIDE, b1_iu, hl_user, NU,
        mBlocksI);

    // ---- layer 2: gather hl h1 -> hl agg; GEMM (A1 hl, in-place) -> fp32 d_out
    gather2k<1><<<gBlocksI + gBlocksU, TPB, 0, stream>>>(
        hl_user, rp_uc, col_uc, colp_uc, agg_i, NI,
        hl_item, rp_iu, col_iu, colp_iu, agg_u, NU, gBlocksI);
    gemm2k<0, 0, 0><<<mBlocksI + mBlocksU, TPB, 0, stream>>>(
        hl_item, agg_i, WTH + 2 * WSTRIDE, WTL + 2 * WSTRIDE, b2_uc, f_item, NI,
        hl_user, agg_u, WTH + 3 * WSTRIDE, WTL + 3 * WSTRIDE, b2_iu, f_user, NU,
        mBlocksI);
}

// Round 14
// 588.382 us; speedup vs baseline: 1.1218x; 1.0495x over previous
//
#include <hip/hip_runtime.h>
#include <hip/hip_bf16.h>

#define D_ 128

typedef __attribute__((ext_vector_type(8))) short s8b;   // 8 bf16
typedef __attribute__((ext_vector_type(4))) float f4;    // MFMA acc

union U4 { uint u[4]; s8b v; uint4 q; };

// async global->LDS, 16B per lane, dest = uniform base + lane*16 (linear)
__device__ __forceinline__ void gl16(const void* g, void* lds) {
    __builtin_amdgcn_global_load_lds(
        (const __attribute__((address_space(1))) void*)g,
        (__attribute__((address_space(3))) void*)lds, 16, 0, 0);
}

// split two fp32 into packed bf16 high (truncate) + low (RNE of residual)
__device__ __forceinline__ void split2(float f0, float f1, uint& hp, uint& lp) {
    uint u0 = __float_as_uint(f0), u1 = __float_as_uint(f1);
    hp = (u0 >> 16) | (u1 & 0xffff0000u);
    float r0 = f0 - __uint_as_float(u0 & 0xffff0000u);
    float r1 = f1 - __uint_as_float(u1 & 0xffff0000u);
    uint v0 = __float_as_uint(r0), v1 = __float_as_uint(r1);
    uint l0 = (v0 + 0x7fffu + ((v0 >> 16) & 1u)) >> 16;
    uint l1 = (v1 + 0x7fffu + ((v1 >> 16) & 1u)) >> 16;
    lp = l0 | (l1 << 16);
}

// ---------------- degree (both relations) ----------------
__global__ void deg2_kernel(const int* __restrict__ dstA, const int* __restrict__ dstB,
                            int* __restrict__ degA, int* __restrict__ degB, int E) {
    int e = blockIdx.x * blockDim.x + threadIdx.x;
    const int* dst = blockIdx.y ? dstB : dstA;
    int* deg = blockIdx.y ? degB : degA;
    if (e < E) atomicAdd(&deg[dst[e]], 1);
}

// ---------------- exclusive scan (3-kernel, both relations) ----------------
__global__ __launch_bounds__(256)
void scan1m(const int* __restrict__ degA, const int* __restrict__ degB,
            int* __restrict__ rpA, int* __restrict__ rpB,
            int* __restrict__ partA, int* __restrict__ partB, int N) {
    const int* deg = blockIdx.y ? degB : degA;
    int* rp = blockIdx.y ? rpB : rpA;
    int* partials = blockIdx.y ? partB : partA;
    int tid = threadIdx.x;
    int i = blockIdx.x * 256 + tid;
    int v = (i < N) ? deg[i] : 0;
    int lane = tid & 63, wid = tid >> 6;
    int x = v;
#pragma unroll
    for (int off = 1; off < 64; off <<= 1) {
        int y = __shfl_up(x, off, 64);
        if (lane >= off) x += y;
    }
    __shared__ int wsum[5];
    if (lane == 63) wsum[wid] = x;
    __syncthreads();
    if (tid == 0) {
        int a = wsum[0], b = wsum[1], c = wsum[2], d = wsum[3];
        wsum[0] = 0; wsum[1] = a; wsum[2] = a + b; wsum[3] = a + b + c;
        wsum[4] = a + b + c + d;
    }
    __syncthreads();
    if (i < N) rp[i] = wsum[wid] + x - v;
    if (tid == 0) partials[blockIdx.x] = wsum[4];
}

__global__ __launch_bounds__(1024)
void scan2m(int* __restrict__ partA, int* __restrict__ partB, int B) {
    int* partials = blockIdx.x ? partB : partA;
    __shared__ int buf[1024];
    int t = threadIdx.x;
    int v = (t < B) ? partials[t] : 0;
    buf[t] = v;
    __syncthreads();
    for (int off = 1; off < 1024; off <<= 1) {
        int add = (t >= off) ? buf[t - off] : 0;
        __syncthreads();
        buf[t] += add;
        __syncthreads();
    }
    if (t < B) partials[t] = buf[t] - v;
}

__global__ __launch_bounds__(256)
void scan3m(int* __restrict__ rpA, int* __restrict__ rpB,
            const int* __restrict__ partA, const int* __restrict__ partB, int N, int E) {
    int* rp = blockIdx.y ? rpB : rpA;
    const int* partials = blockIdx.y ? partB : partA;
    int i = blockIdx.x * 256 + threadIdx.x;
    if (i < N) rp[i] += partials[blockIdx.x];
    if (i == 0) rp[N] = E;
}

// ---------------- CSR fill (both relations) + first-4 pack ----------------
__global__ void fill2_csr(const int* __restrict__ srcA, const int* __restrict__ dstA,
                          const int* __restrict__ rpA, int* __restrict__ curA,
                          int* __restrict__ colA, int* __restrict__ colpA,
                          const int* __restrict__ srcB, const int* __restrict__ dstB,
                          const int* __restrict__ rpB, int* __restrict__ curB,
                          int* __restrict__ colB, int* __restrict__ colpB, int E) {
    int e = blockIdx.x * blockDim.x + threadIdx.x;
    if (e >= E) return;
    const int* src = blockIdx.y ? srcB : srcA;
    const int* dst = blockIdx.y ? dstB : dstA;
    const int* rp  = blockIdx.y ? rpB : rpA;
    int* cursor = blockIdx.y ? curB : curA;
    int* col    = blockIdx.y ? colB : colA;
    int* colp   = blockIdx.y ? colpB : colpA;
    int d = dst[e];
    int s = src[e];
    int idx = atomicAdd(&cursor[d], 1);
    col[rp[d] + idx] = s;
    if (idx < 4) colp[d * 4 + idx] = s;
}

// ---------------- weight prep: transpose + bf16 h/l split ----------------
// WT layout per config g: [col 0..127][kv 0..255] (kv<128 self, >=128 neigh)
__global__ __launch_bounds__(256)
void prep_weights(const float* __restrict__ s0, const float* __restrict__ n0,
                  const float* __restrict__ s1, const float* __restrict__ n1,
                  const float* __restrict__ s2, const float* __restrict__ n2,
                  const float* __restrict__ s3, const float* __restrict__ n3,
                  ushort* __restrict__ WTH, ushort* __restrict__ WTL) {
    int g = blockIdx.y;
    int t = blockIdx.x * 256 + threadIdx.x;   // 0..4095
    int c = t & 127;
    int oct = t >> 7;                          // 0..31 (8 kv each)
    const float* self  = g == 0 ? s0 : g == 1 ? s1 : g == 2 ? s2 : s3;
    const float* neigh = g == 0 ? n0 : g == 1 ? n1 : g == 2 ? n2 : n3;
    uint hd[4], ld_[4];
#pragma unroll
    for (int p = 0; p < 4; ++p) {
        uint hpair = 0, lpair = 0;
#pragma unroll
        for (int q = 0; q < 2; ++q) {
            int kv = oct * 8 + p * 2 + q;
            const float* Wsrc = kv < 128 ? self : neigh;
            float f = Wsrc[(size_t)(kv & 127) * 128 + c];
            uint u = __float_as_uint(f);
            uint h = u >> 16;
            float r = f - __uint_as_float(u & 0xffff0000u);
            uint v = __float_as_uint(r);
            uint l = (v + 0x7fffu + ((v >> 16) & 1u)) >> 16;
            hpair |= h << (16 * q);
            lpair |= l << (16 * q);
        }
        hd[p] = hpair; ld_[p] = lpair;
    }
    size_t base = ((size_t)g * 128 + c) * 256 + oct * 8;
    *(uint4*)(WTH + base) = make_uint4(hd[0], hd[1], hd[2], hd[3]);
    *(uint4*)(WTL + base) = make_uint4(ld_[0], ld_[1], ld_[2], ld_[3]);
}

// ---------------- FUSED gather-mean + dual GEMM ----------------
// Per block: 64 dst rows. Phase 1: gather neighbor-mean into LDS (hl, resident).
// Phase 2: K-loop, 8 steps of 32: ks 0-3 A1 streamed, ks 4-7 agg RESIDENT (no staging).
// out[64,128] = A1@W_self + mean@W_neigh + bias. 512 threads = 8 waves of 32x32.
// LDS: AggH[0,16K) AggL[16K,32K) Astep[32K,40K) Wh[40K,48K) Wl[48K,56K). Epilogue T reuses [0,33.8K).
#define AGGH 0
#define AGGL 16384
#define ASTEP 32768
#define WHO 40960
#define WLO 49152

template<int FP32IN, int SPLIT, int LRELU>
__device__ __forceinline__ void fused_body(const char* A1, const char* XN,
        const int* rp, const int* col, const int* colp,
        const ushort* WTh, const ushort* WTl, const float* bias, void* outp,
        int bid, char* smem) {
    const int t = threadIdx.x;
    const int row0 = bid * 64;

    // ---- phase 1: gather (64 nodes, 16 lanes/node, 2 passes)
    {
        const int li = t & 15;
#pragma unroll
        for (int pass = 0; pass < 2; ++pass) {
            int nl = pass * 32 + (t >> 4);      // 0..63
            int node = row0 + nl;
            int beg = rp[node], end = rp[node + 1];
            int dg = end - beg;
            int4 c4 = *(const int4*)(colp + (size_t)node * 4);
            int s0 = dg > 0 ? c4.x : 0;
            int s1 = dg > 1 ? c4.y : 0;
            int s2 = dg > 2 ? c4.z : 0;
            int s3 = dg > 3 ? c4.w : 0;
            float w0 = dg > 0 ? 1.f : 0.f;
            float w1 = dg > 1 ? 1.f : 0.f;
            float w2 = dg > 2 ? 1.f : 0.f;
            float w3 = dg > 3 ? 1.f : 0.f;
            float a[8];
#pragma unroll
            for (int j = 0; j < 8; ++j) a[j] = 0.f;
            if (FP32IN) {
                const char* p0 = XN + (size_t)s0 * 512 + li * 32;
                const char* p1 = XN + (size_t)s1 * 512 + li * 32;
                const char* p2 = XN + (size_t)s2 * 512 + li * 32;
                const char* p3 = XN + (size_t)s3 * 512 + li * 32;
                float4 A0 = *(const float4*)p0, B0 = *(const float4*)(p0 + 16);
                float4 A1v = *(const float4*)p1, B1 = *(const float4*)(p1 + 16);
                float4 A2v = *(const float4*)p2, B2 = *(const float4*)(p2 + 16);
                float4 A3v = *(const float4*)p3, B3 = *(const float4*)(p3 + 16);
                float e0[8] = {A0.x, A0.y, A0.z, A0.w, B0.x, B0.y, B0.z, B0.w};
                float e1[8] = {A1v.x, A1v.y, A1v.z, A1v.w, B1.x, B1.y, B1.z, B1.w};
                float e2[8] = {A2v.x, A2v.y, A2v.z, A2v.w, B2.x, B2.y, B2.z, B2.w};
                float e3[8] = {A3v.x, A3v.y, A3v.z, A3v.w, B3.x, B3.y, B3.z, B3.w};
#pragma unroll
                for (int j = 0; j < 8; ++j)
                    a[j] = e0[j] * w0 + e1[j] * w1 + e2[j] * w2 + e3[j] * w3;
                for (int e = beg + 4; e < end; ++e) {
                    const char* p = XN + (size_t)col[e] * 512 + li * 32;
                    float4 X = *(const float4*)p, Y = *(const float4*)(p + 16);
                    a[0] += X.x; a[1] += X.y; a[2] += X.z; a[3] += X.w;
                    a[4] += Y.x; a[5] += Y.y; a[6] += Y.z; a[7] += Y.w;
                }
            } else {
                const char* p0 = XN + (size_t)s0 * 512 + li * 16;
                const char* p1 = XN + (size_t)s1 * 512 + li * 16;
                const char* p2 = XN + (size_t)s2 * 512 + li * 16;
                const char* p3 = XN + (size_t)s3 * 512 + li * 16;
                uint4 H0 = *(const uint4*)p0, L0 = *(const uint4*)(p0 + 256);
                uint4 H1 = *(const uint4*)p1, L1 = *(const uint4*)(p1 + 256);
                uint4 H2 = *(const uint4*)p2, L2 = *(const uint4*)(p2 + 256);
                uint4 H3 = *(const uint4*)p3, L3 = *(const uint4*)(p3 + 256);
                const ushort* hu; const ushort* lu;
#pragma unroll
                for (int q = 0; q < 4; ++q) {
                    uint4 H = q == 0 ? H0 : q == 1 ? H1 : q == 2 ? H2 : H3;
                    uint4 L = q == 0 ? L0 : q == 1 ? L1 : q == 2 ? L2 : L3;
                    float wq = q == 0 ? w0 : q == 1 ? w1 : q == 2 ? w2 : w3;
                    hu = (const ushort*)&H; lu = (const ushort*)&L;
#pragma unroll
                    for (int j = 0; j < 8; ++j) {
                        float v = __uint_as_float((uint)hu[j] << 16)
                                + __uint_as_float((uint)lu[j] << 16);
                        a[j] = fmaf(v, wq, a[j]);
                    }
                }
                for (int e = beg + 4; e < end; ++e) {
                    const char* p = XN + (size_t)col[e] * 512 + li * 16;
                    uint4 H = *(const uint4*)p, L = *(const uint4*)(p + 256);
                    hu = (const ushort*)&H; lu = (const ushort*)&L;
#pragma unroll
                    for (int j = 0; j < 8; ++j)
                        a[j] += __uint_as_float((uint)hu[j] << 16)
                              + __uint_as_float((uint)lu[j] << 16);
                }
            }
            float inv = 1.f / (float)(dg > 0 ? dg : 1);
            uint h[4], l[4];
            split2(a[0] * inv, a[1] * inv, h[0], l[0]);
            split2(a[2] * inv, a[3] * inv, h[1], l[1]);
            split2(a[4] * inv, a[5] * inv, h[2], l[2]);
            split2(a[6] * inv, a[7] * inv, h[3], l[3]);
            int chunk = li ^ (nl & 3) ^ (((nl >> 2) & 3) << 2);   // involution
            *(uint4*)(smem + AGGH + nl * 256 + chunk * 16) = make_uint4(h[0], h[1], h[2], h[3]);
            *(uint4*)(smem + AGGL + nl * 256 + chunk * 16) = make_uint4(l[0], l[1], l[2], l[3]);
        }
    }
    __syncthreads();

    // ---- phase 2: K-loop
    const int w = t >> 6, lane = t & 63;
    const int fr = lane & 15, hi = lane >> 4;
    const int mrow0 = (w & 1) * 32, ncol0 = (w >> 1) * 32;

    f4 acc[2][2];
    {
        float bv[2];
#pragma unroll
        for (int n = 0; n < 2; ++n) bv[n] = bias[ncol0 + n * 16 + fr];
#pragma unroll
        for (int m = 0; m < 2; ++m)
#pragma unroll
            for (int n = 0; n < 2; ++n) acc[m][n] = (f4){bv[n], bv[n], bv[n], bv[n]};
    }

    for (int ks = 0; ks < 8; ++ks) {
        // stage A1 (ks<4 only) and W
        if (ks < 4) {
            if (FP32IN) {
                int row = t >> 3, cs = t & 7;
                gl16(A1 + (size_t)(row0 + row) * 512 + ks * 128 + ((cs ^ (row & 7)) * 16),
                     smem + ASTEP + t * 16);
            } else {
                int j = t & 255, part = t >> 8;
                int row = j >> 2, cs = j & 3;
                gl16(A1 + (size_t)(row0 + row) * 512 + part * 256 + ks * 64
                         + ((cs ^ ((row >> 1) & 3)) * 16),
                     smem + ASTEP + part * 4096 + j * 16);
            }
        }
        {
            int col_ = t >> 2, cs = t & 3;
            size_t so = (size_t)col_ * 512 + ks * 64 + ((cs ^ ((col_ >> 1) & 3)) * 16);
            gl16((const char*)WTh + so, smem + WHO + t * 16);
            gl16((const char*)WTl + so, smem + WLO + t * 16);
        }
        __syncthreads();

        s8b ah[2], al[2], wh[2], wl[2];
        if (ks < 4) {
            if (FP32IN) {
#pragma unroll
                for (int m = 0; m < 2; ++m) {
                    int r = mrow0 + m * 16 + fr;
                    f4 x0 = *(const f4*)(smem + ASTEP + r * 128 + (((hi * 2) ^ (r & 7)) * 16));
                    f4 x1 = *(const f4*)(smem + ASTEP + r * 128 + (((hi * 2 + 1) ^ (r & 7)) * 16));
                    U4 H, L;
                    split2(x0[0], x0[1], H.u[0], L.u[0]);
                    split2(x0[2], x0[3], H.u[1], L.u[1]);
                    split2(x1[0], x1[1], H.u[2], L.u[2]);
                    split2(x1[2], x1[3], H.u[3], L.u[3]);
                    ah[m] = H.v; al[m] = L.v;
                }
            } else {
#pragma unroll
                for (int m = 0; m < 2; ++m) {
                    int r = mrow0 + m * 16 + fr;
                    int off = r * 64 + ((hi ^ ((r >> 1) & 3)) * 16);
                    ah[m] = *(const s8b*)(smem + ASTEP + off);
                    al[m] = *(const s8b*)(smem + ASTEP + 4096 + off);
                }
            }
        } else {
            int kk = ks - 4;
#pragma unroll
            for (int m = 0; m < 2; ++m) {
                int r = mrow0 + m * 16 + fr;
                int chunk = (kk * 4 + hi) ^ (r & 3) ^ (((r >> 2) & 3) << 2);
                ah[m] = *(const s8b*)(smem + AGGH + r * 256 + chunk * 16);
                al[m] = *(const s8b*)(smem + AGGL + r * 256 + chunk * 16);
            }
        }
#pragma unroll
        for (int n = 0; n < 2; ++n) {
            int c = ncol0 + n * 16 + fr;
            int off = c * 64 + ((hi ^ ((c >> 1) & 3)) * 16);
            wh[n] = *(const s8b*)(smem + WHO + off);
            wl[n] = *(const s8b*)(smem + WLO + off);
        }
#pragma unroll
        for (int n = 0; n < 2; ++n)
#pragma unroll
            for (int m = 0; m < 2; ++m) {
                acc[m][n] = __builtin_amdgcn_mfma_f32_16x16x32_bf16(ah[m], wh[n], acc[m][n], 0, 0, 0);
                acc[m][n] = __builtin_amdgcn_mfma_f32_16x16x32_bf16(al[m], wh[n], acc[m][n], 0, 0, 0);
                acc[m][n] = __builtin_amdgcn_mfma_f32_16x16x32_bf16(ah[m], wl[n], acc[m][n], 0, 0, 0);
            }
        __syncthreads();
    }

    // ---- epilogue: LDS transpose (64x132 fp32 = 33.8KB, reuses Agg region) + coalesced stores
    float* T = (float*)smem;
#pragma unroll
    for (int m = 0; m < 2; ++m)
#pragma unroll
        for (int n = 0; n < 2; ++n)
#pragma unroll
            for (int r = 0; r < 4; ++r)
                T[(mrow0 + m * 16 + hi * 4 + r) * 132 + ncol0 + n * 16 + fr] = acc[m][n][r];
    __syncthreads();
    {
        int row = t >> 3, q = t & 7;            // 8 lanes per row
        int gr = row0 + row;
        if (SPLIT) {
            char* ob = (char*)outp + (size_t)gr * 512;
#pragma unroll
            for (int i = 0; i < 2; ++i) {
                const float* p = T + row * 132 + (q * 2 + i) * 8;
                f4 x0 = *(const f4*)p;
                f4 x1 = *(const f4*)(p + 4);
                float e[8] = {x0[0], x0[1], x0[2], x0[3], x1[0], x1[1], x1[2], x1[3]};
                if (LRELU) {
#pragma unroll
                    for (int j = 0; j < 8; ++j) e[j] = e[j] > 0.f ? e[j] : 0.01f * e[j];
                }
                uint h[4], l[4];
#pragma unroll
                for (int j = 0; j < 4; ++j) split2(e[2 * j], e[2 * j + 1], h[j], l[j]);
                *(uint4*)(ob + (q * 2 + i) * 16) = make_uint4(h[0], h[1], h[2], h[3]);
                *(uint4*)(ob + 256 + (q * 2 + i) * 16) = make_uint4(l[0], l[1], l[2], l[3]);
            }
        } else {
            float* ob = (float*)outp + (size_t)gr * 128;
#pragma unroll
            for (int i = 0; i < 4; ++i) {
                f4 x = *(const f4*)(T + row * 132 + q * 16 + i * 4);
                float e0 = x[0], e1 = x[1], e2 = x[2], e3 = x[3];
                if (LRELU) {
                    e0 = e0 > 0.f ? e0 : 0.01f * e0;
                    e1 = e1 > 0.f ? e1 : 0.01f * e1;
                    e2 = e2 > 0.f ? e2 : 0.01f * e2;
                    e3 = e3 > 0.f ? e3 : 0.01f * e3;
                }
                *(float4*)(ob + q * 16 + i * 4) = make_float4(e0, e1, e2, e3);
            }
        }
    }
}

template<int FP32IN, int SPLIT, int LRELU>
__global__ __launch_bounds__(512, 2)
void fused2k(const void* A1a, const void* XNa, const int* rpA, const int* colA,
             const int* colpA, const ushort* WTha, const ushort* WTla,
             const float* ba, void* outa,
             const void* A1b, const void* XNb, const int* rpB, const int* colB,
             const int* colpB, const ushort* WThb, const ushort* WTlb,
             const float* bb, void* outb, int blocksA) {
    __shared__ __align__(16) char smem[57344];
    bool isA = (int)blockIdx.x < blocksA;
    int bid = isA ? blockIdx.x : blockIdx.x - blocksA;
    if (isA)
        fused_body<FP32IN, SPLIT, LRELU>((const char*)A1a, (const char*)XNa, rpA, colA,
                                         colpA, WTha, WTla, ba, outa, bid, smem);
    else
        fused_body<FP32IN, SPLIT, LRELU>((const char*)A1b, (const char*)XNb, rpB, colB,
                                         colpB, WThb, WTlb, bb, outb, bid, smem);
}

extern "C" void kernel_launch(void* const* d_in, const int* in_sizes, int n_in,
                              void* d_out, int out_size, void* d_ws, size_t ws_size,
                              hipStream_t stream) {
    const float* x_user     = (const float*)d_in[0];
    const float* x_item     = (const float*)d_in[1];
    const float* w1_self_uc = (const float*)d_in[2];
    const float* w1_neigh_uc= (const float*)d_in[3];
    const float* b1_uc      = (const float*)d_in[4];
    const float* w1_self_iu = (const float*)d_in[5];
    const float* w1_neigh_iu= (const float*)d_in[6];
    const float* b1_iu      = (const float*)d_in[7];
    const float* w2_self_uc = (const float*)d_in[8];
    const float* w2_neigh_uc= (const float*)d_in[9];
    const float* b2_uc      = (const float*)d_in[10];
    const float* w2_self_iu = (const float*)d_in[11];
    const float* w2_neigh_iu= (const float*)d_in[12];
    const float* b2_iu      = (const float*)d_in[13];
    const int* src_uc = (const int*)d_in[14];
    const int* dst_uc = (const int*)d_in[15];
    const int* src_iu = (const int*)d_in[16];
    const int* dst_iu = (const int*)d_in[17];

    const int NU = in_sizes[0] / D_;
    const int NI = in_sizes[1] / D_;
    const int E  = in_sizes[14];

    float* f_user = (float*)d_out;
    float* f_item = (float*)d_out + (size_t)NU * 128;

    // workspace layout: h1 (hl form) lives in ws; d_out written only by layer 2
    char* ws = (char*)d_ws;
    const size_t FEAT_BYTES = (size_t)200000 * 512;      // 102.4 MB (hl rows)
    char* h1_item  = ws;          ws += FEAT_BYTES;
    char* h1_user  = ws;          ws += FEAT_BYTES;
    ushort* WTH    = (ushort*)ws; ws += (size_t)4 * 128 * 256 * sizeof(ushort);
    ushort* WTL    = (ushort*)ws; ws += (size_t)4 * 128 * 256 * sizeof(ushort);
    int* colp_uc   = (int*)ws;    ws += (size_t)200000 * 4 * sizeof(int);
    int* colp_iu   = (int*)ws;    ws += (size_t)200000 * 4 * sizeof(int);
    int* rp_uc     = (int*)ws;    ws += (size_t)(NI + 1) * sizeof(int);
    int* rp_iu     = (int*)ws;    ws += (size_t)(NU + 1) * sizeof(int);
    int* col_uc    = (int*)ws;    ws += (size_t)E * sizeof(int);
    int* col_iu    = (int*)ws;    ws += (size_t)E * sizeof(int);
    int* deg_uc    = (int*)ws;    ws += (size_t)200000 * sizeof(int);
    int* deg_iu    = (int*)ws;    ws += (size_t)200000 * sizeof(int);
    int* cur_uc    = (int*)ws;    ws += (size_t)200000 * sizeof(int);
    int* cur_iu    = (int*)ws;    ws += (size_t)200000 * sizeof(int);
    int* partA     = (int*)ws;    ws += (size_t)1024 * sizeof(int);
    int* partB     = (int*)ws;    ws += (size_t)1024 * sizeof(int);

    const int TPB = 256;
    const int eBlocks  = (E + TPB - 1) / TPB;
    const int sBlocks  = (200000 + 255) / 256;
    const int mBlocksI = (NI + 63) / 64;
    const int mBlocksU = (NU + 63) / 64;
    const size_t WSTRIDE = (size_t)128 * 256;  // g0=l1_uc g1=l1_iu g2=l2_uc g3=l2_iu

    hipMemsetAsync(deg_uc, 0, (size_t)4 * 200000 * sizeof(int), stream); // deg+cursor both rel

    prep_weights<<<dim3(16, 4), 256, 0, stream>>>(
        w1_self_uc, w1_neigh_uc, w1_self_iu, w1_neigh_iu,
        w2_self_uc, w2_neigh_uc, w2_self_iu, w2_neigh_iu, WTH, WTL);

    deg2_kernel<<<dim3(eBlocks, 2), TPB, 0, stream>>>(dst_uc, dst_iu, deg_uc, deg_iu, E);
    scan1m<<<dim3(sBlocks, 2), 256, 0, stream>>>(deg_uc, deg_iu, rp_uc, rp_iu, partA, partB, 200000);
    scan2m<<<2, 1024, 0, stream>>>(partA, partB, sBlocks);
    scan3m<<<dim3(sBlocks, 2), 256, 0, stream>>>(rp_uc, rp_iu, partA, partB, 200000, E);
    fill2_csr<<<dim3(eBlocks, 2), TPB, 0, stream>>>(src_uc, dst_uc, rp_uc, cur_uc, col_uc, colp_uc,
                                                    src_iu, dst_iu, rp_iu, cur_iu, col_iu, colp_iu, E);

    // ---- layer 1 (fused): item side gathers x_user via uc-CSR; user side gathers x_item
    fused2k<1, 1, 1><<<mBlocksI + mBlocksU, 512, 0, stream>>>(
        x_item, x_user, rp_uc, col_uc, colp_uc, WTH + 0 * WSTRIDE, WTL + 0 * WSTRIDE,
        b1_uc, h1_item,
        x_user, x_item, rp_iu, col_iu, colp_iu, WTH + 1 * WSTRIDE, WTL + 1 * WSTRIDE,
        b1_iu, h1_user, mBlocksI);

    // ---- layer 2 (fused): reads h1 from ws, writes fp32 d_out (no aliasing)
    fused2k<0, 0, 0><<<mBlocksI + mBlocksU, 512, 0, stream>>>(
        h1_item, h1_user, rp_uc, col_uc, colp_uc, WTH + 2 * WSTRIDE, WTL + 2 * WSTRIDE,
        b2_uc, f_item,
        h1_user, h1_item, rp_iu, col_iu, colp_iu, WTH + 3 * WSTRIDE, WTL + 3 * WSTRIDE,
        b2_iu, f_user, mBlocksI);
}

// Round 15
// 582.927 us; speedup vs baseline: 1.1323x; 1.0094x over previous
//
#include <hip/hip_runtime.h>
#include <hip/hip_bf16.h>

#define D_ 128

typedef __attribute__((ext_vector_type(8))) short s8b;   // 8 bf16
typedef __attribute__((ext_vector_type(4))) float f4;    // MFMA acc

union U4 { uint u[4]; s8b v; uint4 q; };

// async global->LDS, 16B per lane, dest = uniform base + lane*16 (linear)
__device__ __forceinline__ void gl16(const void* g, void* lds) {
    __builtin_amdgcn_global_load_lds(
        (const __attribute__((address_space(1))) void*)g,
        (__attribute__((address_space(3))) void*)lds, 16, 0, 0);
}

// split two fp32 into packed bf16 high (truncate) + low (RNE of residual)
__device__ __forceinline__ void split2(float f0, float f1, uint& hp, uint& lp) {
    uint u0 = __float_as_uint(f0), u1 = __float_as_uint(f1);
    hp = (u0 >> 16) | (u1 & 0xffff0000u);
    float r0 = f0 - __uint_as_float(u0 & 0xffff0000u);
    float r1 = f1 - __uint_as_float(u1 & 0xffff0000u);
    uint v0 = __float_as_uint(r0), v1 = __float_as_uint(r1);
    uint l0 = (v0 + 0x7fffu + ((v0 >> 16) & 1u)) >> 16;
    uint l1 = (v1 + 0x7fffu + ((v1 >> 16) & 1u)) >> 16;
    lp = l0 | (l1 << 16);
}

__device__ __forceinline__ float4 asf4(uint4 u) {
    return make_float4(__uint_as_float(u.x), __uint_as_float(u.y),
                       __uint_as_float(u.z), __uint_as_float(u.w));
}

// ---------------- degree (both relations) ----------------
__global__ void deg2_kernel(const int* __restrict__ dstA, const int* __restrict__ dstB,
                            int* __restrict__ degA, int* __restrict__ degB, int E) {
    int e = blockIdx.x * blockDim.x + threadIdx.x;
    const int* dst = blockIdx.y ? dstB : dstA;
    int* deg = blockIdx.y ? degB : degA;
    if (e < E) atomicAdd(&deg[dst[e]], 1);
}

// ---------------- exclusive scan (3-kernel, both relations) ----------------
__global__ __launch_bounds__(256)
void scan1m(const int* __restrict__ degA, const int* __restrict__ degB,
            int* __restrict__ rpA, int* __restrict__ rpB,
            int* __restrict__ partA, int* __restrict__ partB, int N) {
    const int* deg = blockIdx.y ? degB : degA;
    int* rp = blockIdx.y ? rpB : rpA;
    int* partials = blockIdx.y ? partB : partA;
    int tid = threadIdx.x;
    int i = blockIdx.x * 256 + tid;
    int v = (i < N) ? deg[i] : 0;
    int lane = tid & 63, wid = tid >> 6;
    int x = v;
#pragma unroll
    for (int off = 1; off < 64; off <<= 1) {
        int y = __shfl_up(x, off, 64);
        if (lane >= off) x += y;
    }
    __shared__ int wsum[5];
    if (lane == 63) wsum[wid] = x;
    __syncthreads();
    if (tid == 0) {
        int a = wsum[0], b = wsum[1], c = wsum[2], d = wsum[3];
        wsum[0] = 0; wsum[1] = a; wsum[2] = a + b; wsum[3] = a + b + c;
        wsum[4] = a + b + c + d;
    }
    __syncthreads();
    if (i < N) rp[i] = wsum[wid] + x - v;
    if (tid == 0) partials[blockIdx.x] = wsum[4];
}

__global__ __launch_bounds__(1024)
void scan2m(int* __restrict__ partA, int* __restrict__ partB, int B) {
    int* partials = blockIdx.x ? partB : partA;
    __shared__ int buf[1024];
    int t = threadIdx.x;
    int v = (t < B) ? partials[t] : 0;
    buf[t] = v;
    __syncthreads();
    for (int off = 1; off < 1024; off <<= 1) {
        int add = (t >= off) ? buf[t - off] : 0;
        __syncthreads();
        buf[t] += add;
        __syncthreads();
    }
    if (t < B) partials[t] = buf[t] - v;
}

__global__ __launch_bounds__(256)
void scan3m(int* __restrict__ rpA, int* __restrict__ rpB,
            const int* __restrict__ partA, const int* __restrict__ partB, int N, int E) {
    int* rp = blockIdx.y ? rpB : rpA;
    const int* partials = blockIdx.y ? partB : partA;
    int i = blockIdx.x * 256 + threadIdx.x;
    if (i < N) rp[i] += partials[blockIdx.x];
    if (i == 0) rp[N] = E;
}

// ---------------- CSR fill (both relations) + first-4 pack ----------------
__global__ void fill2_csr(const int* __restrict__ srcA, const int* __restrict__ dstA,
                          const int* __restrict__ rpA, int* __restrict__ curA,
                          int* __restrict__ colA, int* __restrict__ colpA,
                          const int* __restrict__ srcB, const int* __restrict__ dstB,
                          const int* __restrict__ rpB, int* __restrict__ curB,
                          int* __restrict__ colB, int* __restrict__ colpB, int E) {
    int e = blockIdx.x * blockDim.x + threadIdx.x;
    if (e >= E) return;
    const int* src = blockIdx.y ? srcB : srcA;
    const int* dst = blockIdx.y ? dstB : dstA;
    const int* rp  = blockIdx.y ? rpB : rpA;
    int* cursor = blockIdx.y ? curB : curA;
    int* col    = blockIdx.y ? colB : colA;
    int* colp   = blockIdx.y ? colpB : colpA;
    int d = dst[e];
    int s = src[e];
    int idx = atomicAdd(&cursor[d], 1);
    col[rp[d] + idx] = s;
    if (idx < 4) colp[d * 4 + idx] = s;
}

// ---------------- weight prep: transpose + bf16 h/l split ----------------
// WT layout per config g: [col 0..127][kv 0..255] (kv<128 self, >=128 neigh)
__global__ __launch_bounds__(256)
void prep_weights(const float* __restrict__ s0, const float* __restrict__ n0,
                  const float* __restrict__ s1, const float* __restrict__ n1,
                  const float* __restrict__ s2, const float* __restrict__ n2,
                  const float* __restrict__ s3, const float* __restrict__ n3,
                  ushort* __restrict__ WTH, ushort* __restrict__ WTL) {
    int g = blockIdx.y;
    int t = blockIdx.x * 256 + threadIdx.x;   // 0..4095
    int c = t & 127;
    int oct = t >> 7;                          // 0..31 (8 kv each)
    const float* self  = g == 0 ? s0 : g == 1 ? s1 : g == 2 ? s2 : s3;
    const float* neigh = g == 0 ? n0 : g == 1 ? n1 : g == 2 ? n2 : n3;
    uint hd[4], ld_[4];
#pragma unroll
    for (int p = 0; p < 4; ++p) {
        uint hpair = 0, lpair = 0;
#pragma unroll
        for (int q = 0; q < 2; ++q) {
            int kv = oct * 8 + p * 2 + q;
            const float* Wsrc = kv < 128 ? self : neigh;
            float f = Wsrc[(size_t)(kv & 127) * 128 + c];
            uint u = __float_as_uint(f);
            uint h = u >> 16;
            float r = f - __uint_as_float(u & 0xffff0000u);
            uint v = __float_as_uint(r);
            uint l = (v + 0x7fffu + ((v >> 16) & 1u)) >> 16;
            hpair |= h << (16 * q);
            lpair |= l << (16 * q);
        }
        hd[p] = hpair; ld_[p] = lpair;
    }
    size_t base = ((size_t)g * 128 + c) * 256 + oct * 8;
    *(uint4*)(WTH + base) = make_uint4(hd[0], hd[1], hd[2], hd[3]);
    *(uint4*)(WTL + base) = make_uint4(ld_[0], ld_[1], ld_[2], ld_[3]);
}

// ---------------- FUSED gather-mean + dual GEMM (async gather issue) ----------------
// Per block: 64 dst rows. Gather row-loads ISSUED FIRST (unwaited, 16 uint4 in regs),
// ks0 staging issued next; first barrier drains both. Decode+Agg-LDS-write happens
// after the barrier (overlapped with ks0 MFMA in other waves). K-loop: ks 0-3 A1
// streamed, ks 4-7 agg RESIDENT. 512 threads = 8 waves of 32x32.
// LDS: AggH[0,16K) AggL[16K,32K) Astep[32K,40K) Wh[40K,48K) Wl[48K,56K).
#define AGGH 0
#define AGGL 16384
#define ASTEP 32768
#define WHO 40960
#define WLO 49152

template<int FP32IN, int SPLIT, int LRELU>
__device__ __forceinline__ void fused_body(const char* A1, const char* XN,
        const int* rp, const int* col, const int* colp,
        const ushort* WTh, const ushort* WTl, const float* bias, void* outp,
        int bid, char* smem) {
    const int t = threadIdx.x;
    const int row0 = bid * 64;
    const int li = t & 15;

    // ---- issue gather loads (both passes), no waits
    uint4 GH[2][4], GL[2][4];
    float wv[2][4];
    int begv[2], endv[2], dgv[2];
#pragma unroll
    for (int p = 0; p < 2; ++p) {
        int nl = p * 32 + (t >> 4);
        int node = row0 + nl;
        int beg = rp[node], end = rp[node + 1];
        int dg = end - beg;
        begv[p] = beg; endv[p] = end; dgv[p] = dg;
        int4 c4 = *(const int4*)(colp + (size_t)node * 4);
        int s0 = dg > 0 ? c4.x : 0;
        int s1 = dg > 1 ? c4.y : 0;
        int s2 = dg > 2 ? c4.z : 0;
        int s3 = dg > 3 ? c4.w : 0;
        wv[p][0] = dg > 0 ? 1.f : 0.f;
        wv[p][1] = dg > 1 ? 1.f : 0.f;
        wv[p][2] = dg > 2 ? 1.f : 0.f;
        wv[p][3] = dg > 3 ? 1.f : 0.f;
        const int lo = FP32IN ? li * 32 : li * 16;
        const int d2 = FP32IN ? 16 : 256;
        const char* p0 = XN + (size_t)s0 * 512 + lo;
        const char* p1 = XN + (size_t)s1 * 512 + lo;
        const char* p2 = XN + (size_t)s2 * 512 + lo;
        const char* p3 = XN + (size_t)s3 * 512 + lo;
        GH[p][0] = *(const uint4*)p0; GL[p][0] = *(const uint4*)(p0 + d2);
        GH[p][1] = *(const uint4*)p1; GL[p][1] = *(const uint4*)(p1 + d2);
        GH[p][2] = *(const uint4*)p2; GL[p][2] = *(const uint4*)(p2 + d2);
        GH[p][3] = *(const uint4*)p3; GL[p][3] = *(const uint4*)(p3 + d2);
    }

    // ---- staging helper
    auto stage = [&](int ks) {
        if (ks < 4) {
            if (FP32IN) {
                int row = t >> 3, cs = t & 7;
                gl16(A1 + (size_t)(row0 + row) * 512 + ks * 128 + ((cs ^ (row & 7)) * 16),
                     smem + ASTEP + t * 16);
            } else {
                int j = t & 255, part = t >> 8;
                int row = j >> 2, cs = j & 3;
                gl16(A1 + (size_t)(row0 + row) * 512 + part * 256 + ks * 64
                         + ((cs ^ ((row >> 1) & 3)) * 16),
                     smem + ASTEP + part * 4096 + j * 16);
            }
        }
        {
            int col_ = t >> 2, cs = t & 3;
            size_t so = (size_t)col_ * 512 + ks * 64 + ((cs ^ ((col_ >> 1) & 3)) * 16);
            gl16((const char*)WTh + so, smem + WHO + t * 16);
            gl16((const char*)WTl + so, smem + WLO + t * 16);
        }
    };

    // ---- MFMA setup
    const int w = t >> 6, lane = t & 63;
    const int fr = lane & 15, hi = lane >> 4;
    const int mrow0 = (w & 1) * 32, ncol0 = (w >> 1) * 32;

    f4 acc[2][2];
    {
        float bv[2];
#pragma unroll
        for (int n = 0; n < 2; ++n) bv[n] = bias[ncol0 + n * 16 + fr];
#pragma unroll
        for (int m = 0; m < 2; ++m)
#pragma unroll
            for (int n = 0; n < 2; ++n) acc[m][n] = (f4){bv[n], bv[n], bv[n], bv[n]};
    }

    auto compute = [&](int ks) {
        s8b ah[2], al[2], wh[2], wl[2];
        if (ks < 4) {
            if (FP32IN) {
#pragma unroll
                for (int m = 0; m < 2; ++m) {
                    int r = mrow0 + m * 16 + fr;
                    f4 x0 = *(const f4*)(smem + ASTEP + r * 128 + (((hi * 2) ^ (r & 7)) * 16));
                    f4 x1 = *(const f4*)(smem + ASTEP + r * 128 + (((hi * 2 + 1) ^ (r & 7)) * 16));
                    U4 H, L;
                    split2(x0[0], x0[1], H.u[0], L.u[0]);
                    split2(x0[2], x0[3], H.u[1], L.u[1]);
                    split2(x1[0], x1[1], H.u[2], L.u[2]);
                    split2(x1[2], x1[3], H.u[3], L.u[3]);
                    ah[m] = H.v; al[m] = L.v;
                }
            } else {
#pragma unroll
                for (int m = 0; m < 2; ++m) {
                    int r = mrow0 + m * 16 + fr;
                    int off = r * 64 + ((hi ^ ((r >> 1) & 3)) * 16);
                    ah[m] = *(const s8b*)(smem + ASTEP + off);
                    al[m] = *(const s8b*)(smem + ASTEP + 4096 + off);
                }
            }
        } else {
            int kk = ks - 4;
#pragma unroll
            for (int m = 0; m < 2; ++m) {
                int r = mrow0 + m * 16 + fr;
                int chunk = (kk * 4 + hi) ^ (r & 3) ^ (((r >> 2) & 3) << 2);
                ah[m] = *(const s8b*)(smem + AGGH + r * 256 + chunk * 16);
                al[m] = *(const s8b*)(smem + AGGL + r * 256 + chunk * 16);
            }
        }
#pragma unroll
        for (int n = 0; n < 2; ++n) {
            int c = ncol0 + n * 16 + fr;
            int off = c * 64 + ((hi ^ ((c >> 1) & 3)) * 16);
            wh[n] = *(const s8b*)(smem + WHO + off);
            wl[n] = *(const s8b*)(smem + WLO + off);
        }
#pragma unroll
        for (int n = 0; n < 2; ++n)
#pragma unroll
            for (int m = 0; m < 2; ++m) {
                acc[m][n] = __builtin_amdgcn_mfma_f32_16x16x32_bf16(ah[m], wh[n], acc[m][n], 0, 0, 0);
                acc[m][n] = __builtin_amdgcn_mfma_f32_16x16x32_bf16(al[m], wh[n], acc[m][n], 0, 0, 0);
                acc[m][n] = __builtin_amdgcn_mfma_f32_16x16x32_bf16(ah[m], wl[n], acc[m][n], 0, 0, 0);
            }
    };

    // ---- pipeline: stage ks0 (gather loads already in flight), barrier drains all
    stage(0);
    __syncthreads();

    // ---- decode gather -> Agg LDS (+ rare deg>4 tails); overlaps ks0 MFMA of other waves
#pragma unroll
    for (int p = 0; p < 2; ++p) {
        int nl = p * 32 + (t >> 4);
        float a[8];
#pragma unroll
        for (int j = 0; j < 8; ++j) a[j] = 0.f;
        if (FP32IN) {
#pragma unroll
            for (int q = 0; q < 4; ++q) {
                float4 X = asf4(GH[p][q]);
                float4 Y = asf4(GL[p][q]);
                float wq = wv[p][q];
                a[0] = fmaf(X.x, wq, a[0]); a[1] = fmaf(X.y, wq, a[1]);
                a[2] = fmaf(X.z, wq, a[2]); a[3] = fmaf(X.w, wq, a[3]);
                a[4] = fmaf(Y.x, wq, a[4]); a[5] = fmaf(Y.y, wq, a[5]);
                a[6] = fmaf(Y.z, wq, a[6]); a[7] = fmaf(Y.w, wq, a[7]);
            }
            for (int e = begv[p] + 4; e < endv[p]; ++e) {
                const char* pp = XN + (size_t)col[e] * 512 + li * 32;
                float4 X = *(const float4*)pp, Y = *(const float4*)(pp + 16);
                a[0] += X.x; a[1] += X.y; a[2] += X.z; a[3] += X.w;
                a[4] += Y.x; a[5] += Y.y; a[6] += Y.z; a[7] += Y.w;
            }
        } else {
#pragma unroll
            for (int q = 0; q < 4; ++q) {
                float wq = wv[p][q];
                const ushort* hu = (const ushort*)&GH[p][q];
                const ushort* lu = (const ushort*)&GL[p][q];
#pragma unroll
                for (int j = 0; j < 8; ++j) {
                    float v = __uint_as_float((uint)hu[j] << 16)
                            + __uint_as_float((uint)lu[j] << 16);
                    a[j] = fmaf(v, wq, a[j]);
                }
            }
            for (int e = begv[p] + 4; e < endv[p]; ++e) {
                const char* pp = XN + (size_t)col[e] * 512 + li * 16;
                uint4 H = *(const uint4*)pp, L = *(const uint4*)(pp + 256);
                const ushort* hu = (const ushort*)&H;
                const ushort* lu = (const ushort*)&L;
#pragma unroll
                for (int j = 0; j < 8; ++j)
                    a[j] += __uint_as_float((uint)hu[j] << 16)
                          + __uint_as_float((uint)lu[j] << 16);
            }
        }
        float inv = 1.f / (float)(dgv[p] > 0 ? dgv[p] : 1);
        uint h[4], l[4];
        split2(a[0] * inv, a[1] * inv, h[0], l[0]);
        split2(a[2] * inv, a[3] * inv, h[1], l[1]);
        split2(a[4] * inv, a[5] * inv, h[2], l[2]);
        split2(a[6] * inv, a[7] * inv, h[3], l[3]);
        int chunk = li ^ (nl & 3) ^ (((nl >> 2) & 3) << 2);   // involution
        *(uint4*)(smem + AGGH + nl * 256 + chunk * 16) = make_uint4(h[0], h[1], h[2], h[3]);
        *(uint4*)(smem + AGGL + nl * 256 + chunk * 16) = make_uint4(l[0], l[1], l[2], l[3]);
    }

    // ---- ks0 compute, then remaining K-steps (Agg writes ordered by ks0's end barrier)
    compute(0);
    __syncthreads();
    for (int ks = 1; ks < 8; ++ks) {
        stage(ks);
        __syncthreads();
        compute(ks);
        __syncthreads();
    }

    // ---- epilogue: LDS transpose (64x132 fp32 = 33.8KB, reuses Agg region)
    float* T = (float*)smem;
#pragma unroll
    for (int m = 0; m < 2; ++m)
#pragma unroll
        for (int n = 0; n < 2; ++n)
#pragma unroll
            for (int r = 0; r < 4; ++r)
                T[(mrow0 + m * 16 + hi * 4 + r) * 132 + ncol0 + n * 16 + fr] = acc[m][n][r];
    __syncthreads();
    {
        int row = t >> 3, q = t & 7;            // 8 lanes per row
        int gr = row0 + row;
        if (SPLIT) {
            char* ob = (char*)outp + (size_t)gr * 512;
#pragma unroll
            for (int i = 0; i < 2; ++i) {
                const float* p = T + row * 132 + (q * 2 + i) * 8;
                f4 x0 = *(const f4*)p;
                f4 x1 = *(const f4*)(p + 4);
                float e[8] = {x0[0], x0[1], x0[2], x0[3], x1[0], x1[1], x1[2], x1[3]};
                if (LRELU) {
#pragma unroll
                    for (int j = 0; j < 8; ++j) e[j] = e[j] > 0.f ? e[j] : 0.01f * e[j];
                }
                uint h[4], l[4];
#pragma unroll
                for (int j = 0; j < 4; ++j) split2(e[2 * j], e[2 * j + 1], h[j], l[j]);
                *(uint4*)(ob + (q * 2 + i) * 16) = make_uint4(h[0], h[1], h[2], h[3]);
                *(uint4*)(ob + 256 + (q * 2 + i) * 16) = make_uint4(l[0], l[1], l[2], l[3]);
            }
        } else {
            float* ob = (float*)outp + (size_t)gr * 128;
#pragma unroll
            for (int i = 0; i < 4; ++i) {
                f4 x = *(const f4*)(T + row * 132 + q * 16 + i * 4);
                float e0 = x[0], e1 = x[1], e2 = x[2], e3 = x[3];
                if (LRELU) {
                    e0 = e0 > 0.f ? e0 : 0.01f * e0;
                    e1 = e1 > 0.f ? e1 : 0.01f * e1;
                    e2 = e2 > 0.f ? e2 : 0.01f * e2;
                    e3 = e3 > 0.f ? e3 : 0.01f * e3;
                }
                *(float4*)(ob + q * 16 + i * 4) = make_float4(e0, e1, e2, e3);
            }
        }
    }
}

template<int FP32IN, int SPLIT, int LRELU>
__global__ __launch_bounds__(512, 4)
void fused2k(const void* A1a, const void* XNa, const int* rpA, const int* colA,
             const int* colpA, const ushort* WTha, const ushort* WTla,
             const float* ba, void* outa,
             const void* A1b, const void* XNb, const int* rpB, const int* colB,
             const int* colpB, const ushort* WThb, const ushort* WTlb,
             const float* bb, void* outb, int blocksA) {
    __shared__ __align__(16) char smem[57344];
    bool isA = (int)blockIdx.x < blocksA;
    int bid = isA ? blockIdx.x : blockIdx.x - blocksA;
    if (isA)
        fused_body<FP32IN, SPLIT, LRELU>((const char*)A1a, (const char*)XNa, rpA, colA,
                                         colpA, WTha, WTla, ba, outa, bid, smem);
    else
        fused_body<FP32IN, SPLIT, LRELU>((const char*)A1b, (const char*)XNb, rpB, colB,
                                         colpB, WThb, WTlb, bb, outb, bid, smem);
}

extern "C" void kernel_launch(void* const* d_in, const int* in_sizes, int n_in,
                              void* d_out, int out_size, void* d_ws, size_t ws_size,
                              hipStream_t stream) {
    const float* x_user     = (const float*)d_in[0];
    const float* x_item     = (const float*)d_in[1];
    const float* w1_self_uc = (const float*)d_in[2];
    const float* w1_neigh_uc= (const float*)d_in[3];
    const float* b1_uc      = (const float*)d_in[4];
    const float* w1_self_iu = (const float*)d_in[5];
    const float* w1_neigh_iu= (const float*)d_in[6];
    const float* b1_iu      = (const float*)d_in[7];
    const float* w2_self_uc = (const float*)d_in[8];
    const float* w2_neigh_uc= (const float*)d_in[9];
    const float* b2_uc      = (const float*)d_in[10];
    const float* w2_self_iu = (const float*)d_in[11];
    const float* w2_neigh_iu= (const float*)d_in[12];
    const float* b2_iu      = (const float*)d_in[13];
    const int* src_uc = (const int*)d_in[14];
    const int* dst_uc = (const int*)d_in[15];
    const int* src_iu = (const int*)d_in[16];
    const int* dst_iu = (const int*)d_in[17];

    const int NU = in_sizes[0] / D_;
    const int NI = in_sizes[1] / D_;
    const int E  = in_sizes[14];

    float* f_user = (float*)d_out;
    float* f_item = (float*)d_out + (size_t)NU * 128;

    // workspace layout: h1 (hl form) lives in ws; d_out written only by layer 2
    char* ws = (char*)d_ws;
    const size_t FEAT_BYTES = (size_t)200000 * 512;      // 102.4 MB (hl rows)
    char* h1_item  = ws;          ws += FEAT_BYTES;
    char* h1_user  = ws;          ws += FEAT_BYTES;
    ushort* WTH    = (ushort*)ws; ws += (size_t)4 * 128 * 256 * sizeof(ushort);
    ushort* WTL    = (ushort*)ws; ws += (size_t)4 * 128 * 256 * sizeof(ushort);
    int* colp_uc   = (int*)ws;    ws += (size_t)200000 * 4 * sizeof(int);
    int* colp_iu   = (int*)ws;    ws += (size_t)200000 * 4 * sizeof(int);
    int* rp_uc     = (int*)ws;    ws += (size_t)(NI + 1) * sizeof(int);
    int* rp_iu     = (int*)ws;    ws += (size_t)(NU + 1) * sizeof(int);
    int* col_uc    = (int*)ws;    ws += (size_t)E * sizeof(int);
    int* col_iu    = (int*)ws;    ws += (size_t)E * sizeof(int);
    int* deg_uc    = (int*)ws;    ws += (size_t)200000 * sizeof(int);
    int* deg_iu    = (int*)ws;    ws += (size_t)200000 * sizeof(int);
    int* cur_uc    = (int*)ws;    ws += (size_t)200000 * sizeof(int);
    int* cur_iu    = (int*)ws;    ws += (size_t)200000 * sizeof(int);
    int* partA     = (int*)ws;    ws += (size_t)1024 * sizeof(int);
    int* partB     = (int*)ws;    ws += (size_t)1024 * sizeof(int);

    const int TPB = 256;
    const int eBlocks  = (E + TPB - 1) / TPB;
    const int sBlocks  = (200000 + 255) / 256;
    const int mBlocksI = (NI + 63) / 64;
    const int mBlocksU = (NU + 63) / 64;
    const size_t WSTRIDE = (size_t)128 * 256;  // g0=l1_uc g1=l1_iu g2=l2_uc g3=l2_iu

    hipMemsetAsync(deg_uc, 0, (size_t)4 * 200000 * sizeof(int), stream); // deg+cursor both rel

    prep_weights<<<dim3(16, 4), 256, 0, stream>>>(
        w1_self_uc, w1_neigh_uc, w1_self_iu, w1_neigh_iu,
        w2_self_uc, w2_neigh_uc, w2_self_iu, w2_neigh_iu, WTH, WTL);

    deg2_kernel<<<dim3(eBlocks, 2), TPB, 0, stream>>>(dst_uc, dst_iu, deg_uc, deg_iu, E);
    scan1m<<<dim3(sBlocks, 2), 256, 0, stream>>>(deg_uc, deg_iu, rp_uc, rp_iu, partA, partB, 200000);
    scan2m<<<2, 1024, 0, stream>>>(partA, partB, sBlocks);
    scan3m<<<dim3(sBlocks, 2), 256, 0, stream>>>(rp_uc, rp_iu, partA, partB, 200000, E);
    fill2_csr<<<dim3(eBlocks, 2), TPB, 0, stream>>>(src_uc, dst_uc, rp_uc, cur_uc, col_uc, colp_uc,
                                                    src_iu, dst_iu, rp_iu, cur_iu, col_iu, colp_iu, E);

    // ---- layer 1 (fused): item side gathers x_user via uc-CSR; user side gathers x_item
    fused2k<1, 1, 1><<<mBlocksI + mBlocksU, 512, 0, stream>>>(
        x_item, x_user, rp_uc, col_uc, colp_uc, WTH + 0 * WSTRIDE, WTL + 0 * WSTRIDE,
        b1_uc, h1_item,
        x_user, x_item, rp_iu, col_iu, colp_iu, WTH + 1 * WSTRIDE, WTL + 1 * WSTRIDE,
        b1_iu, h1_user, mBlocksI);

    // ---- layer 2 (fused): reads h1 from ws, writes fp32 d_out (no aliasing)
    fused2k<0, 0, 0><<<mBlocksI + mBlocksU, 512, 0, stream>>>(
        h1_item, h1_user, rp_uc, col_uc, colp_uc, WTH + 2 * WSTRIDE, WTL + 2 * WSTRIDE,
        b2_uc, f_item,
        h1_user, h1_item, rp_iu, col_iu, colp_iu, WTH + 3 * WSTRIDE, WTL + 3 * WSTRIDE,
        b2_iu, f_user, mBlocksI);
}